// Round 9
// baseline (520.385 us; speedup 1.0000x reference)
//
#include <hip/hip_runtime.h>
#include <hip/hip_bf16.h>

// ---------------------------------------------------------------------------
// S4D stack, MFMA everywhere:
// encoder GEMM(+cm,+hfr) -> 4x[ mats; fused SSM (u->LDS swz, state MFMA +
//   LDS scan + Toeplitz conv MFMA); y2pm; GLU MFMA + LN (direct A, hfr
//   residual, writes next ucm) ] -> decoder (reads hfr).
// hfr: f32 fragment-contiguous: chunk tid32=(mi*4+nq)*64+l holds 32 f32:
//   [sub(2)][nj(4)][r(4)] -> row=mi*32+sub*16+(l>>4)*4+r, col=nq*64+nj*16+(l&15)
// ---------------------------------------------------------------------------

constexpr int B_ = 4, L_ = 8192, DIN = 64, H_ = 256, N2_ = 32, NL_ = 4, DOUT = 10;
constexpr int LC = 64, CHK = L_ / LC;     // 128 chunks/batch
constexpr int GCH = B_ * CHK;             // 512 global chunks
constexpr int M_ = B_ * L_;               // 32768 positions

// ws layout in float slots
constexpr size_t OFF_H    = 0;                         // f32 hfr [M*256]
constexpr size_t OFF_WOB  = 8388608;                   // bf16 Wo NL*512*256
constexpr size_t OFF_PW   = 8650752;                   // (legacy)
constexpr size_t OFF_PCT  = 8716288;                   // f32 Ct2 pairs
constexpr size_t OFF_PWLC = 8781824;                   // f32 w^64 pairs
constexpr size_t OFF_PZ   = 8847360;                   // f32 z=dtA pairs
constexpr size_t OFF_EWT  = 8912896;                   // f32 enc W^T
constexpr size_t OFF_UCM  = 8929280;                   // bf16 [H][M] u cm
constexpr size_t OFF_YCM  = 13123584;                  // bf16 [H][M] y cm
constexpr size_t OFF_YPM  = 17317888;                  // bf16 [M][H] y pm
constexpr size_t OFF_MT   = 21512192;                  // bf16 Ttr [H][64][64]
constexpr size_t OFF_MW   = 22036480;                  // bf16 Wtr
constexpr size_t OFF_MV   = 22560768;                  // bf16 Vtr
// end 23085056 slots = 92.3 MB

typedef short bf16x8 __attribute__((ext_vector_type(8)));
typedef short short8 __attribute__((ext_vector_type(8)));
typedef float f32x4  __attribute__((ext_vector_type(4)));

// ---------------------------------------------------------------------------
__global__ __launch_bounds__(256) void k_params(
    const float* __restrict__ log_dt, const float* __restrict__ log_A_re,
    const float* __restrict__ A_im, const float* __restrict__ C_re,
    const float* __restrict__ C_im, float* __restrict__ ws)
{
    int idx = blockIdx.x * 256 + threadIdx.x;     // over NL*H*N2
    if (idx >= NL_ * H_ * N2_) return;
    int i  = idx / (H_ * N2_);
    int hh = (idx / N2_) % H_;
    float dt  = expf(log_dt[i * H_ + hh]);
    float Are = -expf(log_A_re[idx]);
    float Aim = A_im[idx];
    float zre = dt * Are, zim = dt * Aim;
    float er  = expf(zre);
    float wre = er * cosf(zim), wim = er * sinf(zim);
    float d   = Are * Are + Aim * Aim;
    float nre = wre - 1.f, nim = wim;
    float qre = (nre * Are + nim * Aim) / d;
    float qim = (nim * Are - nre * Aim) / d;
    float cr = C_re[idx], ci = C_im[idx];
    float ctre = cr * qre - ci * qim;
    float ctim = cr * qim + ci * qre;
    float er2 = expf(zre * (float)LC);
    float wlre = er2 * cosf(zim * (float)LC);
    float wlim = er2 * sinf(zim * (float)LC);
    ((float2*)(ws + OFF_PW))[idx]   = make_float2(wre, wim);
    ((float2*)(ws + OFF_PCT))[idx]  = make_float2(2.f * ctre, 2.f * ctim);
    ((float2*)(ws + OFF_PWLC))[idx] = make_float2(wlre, wlim);
    ((float2*)(ws + OFF_PZ))[idx]   = make_float2(zre, zim);
}

// ---------------------------------------------------------------------------
// per-channel bf16 matrices: Ttr[t][j]=k[t-j], Wtr[m][j], Vtr[t][m]
__global__ __launch_bounds__(256) void k_mats(const float* __restrict__ ws,
    int layer, __hip_bfloat16* __restrict__ mt, __hip_bfloat16* __restrict__ mw,
    __hip_bfloat16* __restrict__ mv)
{
    int h = blockIdx.x, tid = threadIdx.x;
    __shared__ float zre[32], zim[32], ctr[32], cti[32], kv[64];
    if (tid < 32) {
        float2 z = ((const float2*)(ws + OFF_PZ))[(size_t)layer*H_*N2_ + h*N2_ + tid];
        float2 c = ((const float2*)(ws + OFF_PCT))[(size_t)layer*H_*N2_ + h*N2_ + tid];
        zre[tid] = z.x; zim[tid] = z.y; ctr[tid] = c.x; cti[tid] = c.y;
    }
    __syncthreads();
    if (tid < 64) {
        float d = (float)tid, acc = 0.f;
        for (int n = 0; n < 32; n++) {
            float er = expf(zre[n] * d);
            float co = cosf(zim[n] * d), si = sinf(zim[n] * d);
            acc += er * (ctr[n] * co - cti[n] * si);
        }
        kv[tid] = acc;
    }
    __syncthreads();
    {   // Ttr
        int t = tid >> 2, j0 = (tid & 3) * 16;
        alignas(16) __hip_bfloat16 row[16];
        #pragma unroll
        for (int jj = 0; jj < 16; jj++) {
            int j = j0 + jj;
            row[jj] = __float2bfloat16(j <= t ? kv[t - j] : 0.f);
        }
        *(short8*)(mt + (size_t)h*4096 + t*64 + j0)     = *(short8*)&row[0];
        *(short8*)(mt + (size_t)h*4096 + t*64 + j0 + 8) = *(short8*)&row[8];
    }
    {   // Wtr
        int n = tid >> 3, j0 = (tid & 7) * 8;
        alignas(16) __hip_bfloat16 rre[8], rim[8];
        #pragma unroll
        for (int jj = 0; jj < 8; jj++) {
            float e = (float)(63 - (j0 + jj));
            float er = expf(zre[n] * e);
            rre[jj] = __float2bfloat16(er * cosf(zim[n] * e));
            rim[jj] = __float2bfloat16(er * sinf(zim[n] * e));
        }
        *(short8*)(mw + (size_t)h*4096 + (2*n)*64 + j0)   = *(short8*)&rre[0];
        *(short8*)(mw + (size_t)h*4096 + (2*n+1)*64 + j0) = *(short8*)&rim[0];
    }
    {   // Vtr
        int t = tid >> 2, n0 = (tid & 3) * 8;
        float e = (float)(t + 1);
        alignas(16) __hip_bfloat16 row[16];
        #pragma unroll
        for (int k = 0; k < 8; k++) {
            int n = n0 + k;
            float er = expf(zre[n] * e);
            float wr = er * cosf(zim[n] * e), wi = er * sinf(zim[n] * e);
            row[2*k]   = __float2bfloat16(ctr[n]*wr - cti[n]*wi);
            row[2*k+1] = __float2bfloat16(-(ctr[n]*wi + cti[n]*wr));
        }
        *(short8*)(mv + (size_t)h*4096 + t*64 + 2*n0)     = *(short8*)&row[0];
        *(short8*)(mv + (size_t)h*4096 + t*64 + 2*n0 + 8) = *(short8*)&row[8];
    }
}

// ---------------------------------------------------------------------------
__global__ __launch_bounds__(256) void k_transpose(const float* __restrict__ src,
    float* __restrict__ dst, int R, int Cc)
{
    __shared__ float t[32][33];
    int x = blockIdx.x * 32 + threadIdx.x;
    #pragma unroll
    for (int i = 0; i < 4; i++) {
        int yy = blockIdx.y * 32 + threadIdx.y + i * 8;
        if (x < Cc && yy < R) t[threadIdx.y + i * 8][threadIdx.x] = src[(size_t)yy * Cc + x];
    }
    __syncthreads();
    int xo = blockIdx.y * 32 + threadIdx.x;
    #pragma unroll
    for (int i = 0; i < 4; i++) {
        int yo = blockIdx.x * 32 + threadIdx.y + i * 8;
        if (xo < R && yo < Cc) dst[(size_t)yo * R + xo] = t[threadIdx.x][threadIdx.y + i * 8];
    }
}

// ---------------------------------------------------------------------------
__global__ __launch_bounds__(256) void k_wcvt(const float* __restrict__ src,
    __hip_bfloat16* __restrict__ dst, int n4)
{
    int i = blockIdx.x * 256 + threadIdx.x;
    if (i >= n4) return;
    float4 v = ((const float4*)src)[i];
    union { __hip_bfloat16 b[4]; uint2 u; } o;
    o.b[0] = __float2bfloat16(v.x); o.b[1] = __float2bfloat16(v.y);
    o.b[2] = __float2bfloat16(v.z); o.b[3] = __float2bfloat16(v.w);
    ((uint2*)dst)[i] = o.u;
}

// ---------------------------------------------------------------------------
// encoder: h = x @ encWT + b; writes hfr (fragment layout f32) + ucm bf16 cm
__global__ __launch_bounds__(256) void k_encoder(const float* __restrict__ x,
    const float* __restrict__ encWT, const float* __restrict__ enc_b,
    float* __restrict__ hfr, __hip_bfloat16* __restrict__ ucm)
{
    __shared__ float As[DIN][36];
    __shared__ float Bs[32][268];          // B-tiles; later f32 stage [32 pos][256 ch]
    int m0e = blockIdx.x * 32;
    int tid = threadIdx.x;
    const float4* x4 = (const float4*)x;
    #pragma unroll
    for (int q = 0; q < 2; q++) {
        int f = tid * 2 + q;
        int row = f >> 4, kq = f & 15;
        float4 v = x4[(size_t)(m0e + row) * 16 + kq];
        As[kq * 4 + 0][row] = v.x; As[kq * 4 + 1][row] = v.y;
        As[kq * 4 + 2][row] = v.z; As[kq * 4 + 3][row] = v.w;
    }
    int tx = tid & 31, ty = tid >> 5;
    float acc[4][8];
    #pragma unroll
    for (int p = 0; p < 4; p++)
        #pragma unroll
        for (int j = 0; j < 8; j++) acc[p][j] = 0.f;
    const float4* w4 = (const float4*)encWT;
    for (int ks = 0; ks < 2; ks++) {
        __syncthreads();
        #pragma unroll
        for (int it = 0; it < 8; it++) {
            int q = it * 256 + tid;
            int row = q >> 6, c4 = q & 63;
            *(float4*)&Bs[row][c4 * 4] = w4[ks * 2048 + q];
        }
        __syncthreads();
        #pragma unroll 8
        for (int kk = 0; kk < 32; kk++) {
            int k = ks * 32 + kk;
            float4 a  = *(const float4*)&As[k][ty * 4];
            float4 b0 = *(const float4*)&Bs[kk][tx * 4];
            float4 b1 = *(const float4*)&Bs[kk][128 + tx * 4];
            float av[4] = {a.x, a.y, a.z, a.w};
            float bv[8] = {b0.x, b0.y, b0.z, b0.w, b1.x, b1.y, b1.z, b1.w};
            #pragma unroll
            for (int p = 0; p < 4; p++)
                #pragma unroll
                for (int j = 0; j < 8; j++)
                    acc[p][j] = fmaf(av[p], bv[j], acc[p][j]);
        }
    }
    float4 eb0 = *(const float4*)&enc_b[tx * 4];
    float4 eb1 = *(const float4*)&enc_b[128 + tx * 4];
    float ebv[8] = {eb0.x, eb0.y, eb0.z, eb0.w, eb1.x, eb1.y, eb1.z, eb1.w};
    __syncthreads();                       // Bs dead -> f32 stage st2[pl][ch]
    #pragma unroll
    for (int p = 0; p < 4; p++) {
        int pl = ty * 4 + p;
        #pragma unroll
        for (int j = 0; j < 4; j++) Bs[pl][tx * 4 + j]       = acc[p][j] + ebv[j];
        #pragma unroll
        for (int j = 0; j < 4; j++) Bs[pl][128 + tx * 4 + j] = acc[p][j + 4] + ebv[j + 4];
    }
    __syncthreads();
    // hfr write: fragment threads, 32 contiguous f32 each
    {
        size_t m0 = (size_t)(m0e & ~63);
        int mi = (m0e >> 5) & 1;
        int nq = tid >> 6, l = tid & 63, l4 = l >> 4, l15 = l & 15;
        int tid32 = (mi * 4 + nq) * 64 + l;
        float* dst = hfr + m0 * 256 + (size_t)tid32 * 32;
        #pragma unroll
        for (int sub = 0; sub < 2; sub++)
            #pragma unroll
            for (int nj = 0; nj < 4; nj++) {
                int pl = sub * 16 + l4 * 4;
                int cn = nq * 64 + nj * 16 + l15;
                float4 o = make_float4(Bs[pl][cn], Bs[pl + 1][cn], Bs[pl + 2][cn], Bs[pl + 3][cn]);
                *(float4*)(dst + sub * 16 + nj * 4) = o;
            }
    }
    // ucm write: thread = channel
    {
        alignas(16) __hip_bfloat16 row[32];
        #pragma unroll
        for (int pl = 0; pl < 32; pl++) row[pl] = __float2bfloat16(Bs[pl][tid]);
        #pragma unroll
        for (int q = 0; q < 4; q++)
            *(short8*)(ucm + (size_t)tid * M_ + m0e + q * 8) = *(short8*)&row[q * 8];
    }
}

// ---------------------------------------------------------------------------
// FUSED SSM: block = (channel, batch). u staged in XOR-swizzled LDS.
// Phase1: chunk-state MFMA -> swz LDS. Phase2: serial scan. Phase3: conv MFMA.
// swizzle: elem e within chunk c lives at c*64 + (e ^ ((c&7)<<3))
__global__ __launch_bounds__(256) void k_ssm(const __hip_bfloat16* __restrict__ ucm,
    const __hip_bfloat16* __restrict__ mt, const __hip_bfloat16* __restrict__ mw,
    const __hip_bfloat16* __restrict__ mv, const float* __restrict__ ws, int layer,
    const float* __restrict__ Dp, __hip_bfloat16* __restrict__ ycm)
{
    __shared__ __hip_bfloat16 ulds[L_];       // 16 KB swizzled u
    __shared__ __hip_bfloat16 st[CHK * 64];   // 16 KB swizzled states
    int h = blockIdx.x >> 2, b = blockIdx.x & 3;
    int tid = threadIdx.x, w = tid >> 6, l = tid & 63, l15 = l & 15, l4 = l >> 4;
    const __hip_bfloat16* ub = ucm + (size_t)h * M_ + (size_t)b * L_;
    // ---- stage u -> swizzled LDS
    #pragma unroll
    for (int it = 0; it < 4; it++) {
        int e0 = tid * 32 + it * 8;
        short8 v = *(const short8*)(ub + e0);
        int c = e0 >> 6, e = e0 & 63;
        *(short8*)&ulds[c * 64 + (e ^ ((c & 7) << 3))] = v;
    }
    __syncthreads();
    // ---- phase 1: states S[g][m] = sum_j Wtr[m][j] u[g*64+j]
    {
        const __hip_bfloat16* bbase = mw + (size_t)h * 4096 + l15 * 64 + l4 * 8;
        #pragma unroll
        for (int half = 0; half < 2; half++) {
            int g0 = (w + half * 4) * 16;
            int ca = g0 + l15;
            f32x4 acc[4];
            #pragma unroll
            for (int nj = 0; nj < 4; nj++) acc[nj] = (f32x4)0.f;
            #pragma unroll
            for (int ks = 0; ks < 2; ks++) {
                int e = l4 * 8 + ks * 32;
                bf16x8 a = *(const bf16x8*)&ulds[ca * 64 + (e ^ ((ca & 7) << 3))];
                #pragma unroll
                for (int nj = 0; nj < 4; nj++) {
                    bf16x8 bb = *(const bf16x8*)(bbase + nj * 16 * 64 + ks * 32);
                    acc[nj] = __builtin_amdgcn_mfma_f32_16x16x32_bf16(a, bb, acc[nj], 0, 0, 0);
                }
            }
            #pragma unroll
            for (int nj = 0; nj < 4; nj++)
                #pragma unroll
                for (int r = 0; r < 4; r++) {
                    int c = g0 + l4 * 4 + r, e = nj * 16 + l15;
                    st[c * 64 + (e ^ ((c & 7) << 3))] = __float2bfloat16(acc[nj][r]);
                }
        }
    }
    __syncthreads();
    // ---- phase 2: serial scan over 128 chunks (32 threads)
    if (tid < 32) {
        int n = tid;
        float2 wl = ((const float2*)(ws + OFF_PWLC))[(size_t)layer * H_ * N2_ + h * 32 + n];
        float ar = 0.f, ai = 0.f;
        for (int c = 0; c < CHK; c++) {
            __hip_bfloat162* p = (__hip_bfloat162*)&st[c * 64 + ((2 * n) ^ ((c & 7) << 3))];
            float2 v = __bfloat1622float2(*p);
            *p = __float22bfloat162_rn(make_float2(ar, ai));
            float tr = fmaf(wl.x, ar, v.x); tr = fmaf(-wl.y, ai, tr);
            float ti = fmaf(wl.x, ai, v.y); ti = fmaf(wl.y, ar, ti);
            ar = tr; ai = ti;
        }
    }
    __syncthreads();
    // ---- phase 3: conv + carry + D-skip + GELU
    {
        const __hip_bfloat16* bt = mt + (size_t)h * 4096 + l15 * 64 + l4 * 8;
        const __hip_bfloat16* bv = mv + (size_t)h * 4096 + l15 * 64 + l4 * 8;
        float Dh = Dp[layer * H_ + h];
        __hip_bfloat16* yb = ycm + (size_t)h * M_ + (size_t)b * L_;
        #pragma unroll
        for (int half = 0; half < 2; half++) {
            int g0 = (w + half * 4) * 16;
            int ca = g0 + l15;
            f32x4 acc[4];
            #pragma unroll
            for (int nj = 0; nj < 4; nj++) acc[nj] = (f32x4)0.f;
            #pragma unroll
            for (int ks = 0; ks < 2; ks++) {
                int e = l4 * 8 + ks * 32;
                bf16x8 a = *(const bf16x8*)&ulds[ca * 64 + (e ^ ((ca & 7) << 3))];
                #pragma unroll
                for (int nj = 0; nj < 4; nj++) {
                    bf16x8 bb = *(const bf16x8*)(bt + nj * 16 * 64 + ks * 32);
                    acc[nj] = __builtin_amdgcn_mfma_f32_16x16x32_bf16(a, bb, acc[nj], 0, 0, 0);
                }
            }
            #pragma unroll
            for (int ks = 0; ks < 2; ks++) {
                int e = l4 * 8 + ks * 32;
                bf16x8 a = *(const bf16x8*)&st[ca * 64 + (e ^ ((ca & 7) << 3))];
                #pragma unroll
                for (int nj = 0; nj < 4; nj++) {
                    bf16x8 bb = *(const bf16x8*)(bv + nj * 16 * 64 + ks * 32);
                    acc[nj] = __builtin_amdgcn_mfma_f32_16x16x32_bf16(a, bb, acc[nj], 0, 0, 0);
                }
            }
            #pragma unroll
            for (int nj = 0; nj < 4; nj++)
                #pragma unroll
                for (int r = 0; r < 4; r++) {
                    int g = g0 + l4 * 4 + r;
                    int e = nj * 16 + l15;
                    float uv = __bfloat162float(ulds[g * 64 + (e ^ ((g & 7) << 3))]);
                    float v = fmaf(Dh, uv, acc[nj][r]);
                    float gg = 0.7978845608028654f * fmaf(0.044715f * v, v * v, v);
                    float yv = v / (1.f + __expf(-2.f * gg));
                    yb[(size_t)g * 64 + nj * 16 + l15] = __float2bfloat16(yv);
                }
        }
    }
}

// ---------------------------------------------------------------------------
// y_cm -> y_pm transpose
__global__ __launch_bounds__(256) void k_y2pm(const __hip_bfloat16* __restrict__ ycm,
    __hip_bfloat16* __restrict__ ypm)
{
    __shared__ __hip_bfloat16 lds[64][68];
    int pos0 = blockIdx.x * 64, ch0 = blockIdx.y * 64;
    int tid = threadIdx.x;
    int ch = tid >> 2, p0 = (tid & 3) * 16;
    const __hip_bfloat16* src = ycm + (size_t)(ch0 + ch) * M_ + pos0 + p0;
    #pragma unroll
    for (int k = 0; k < 2; k++)
        *(short8*)&lds[ch][p0 + k*8] = *(const short8*)(src + k*8);
    __syncthreads();
    int pp = tid >> 2, c0 = (tid & 3) * 16;
    alignas(16) __hip_bfloat16 row[16];
    #pragma unroll
    for (int k = 0; k < 16; k++) row[k] = lds[c0 + k][pp];
    size_t base = (size_t)(pos0 + pp) * H_ + ch0 + c0;
    *(short8*)(ypm + base)     = *(short8*)&row[0];
    *(short8*)(ypm + base + 8) = *(short8*)&row[8];
}

// ---------------------------------------------------------------------------
// fused MFMA GLU+LN v6 (round-4 core): BM=64, 256 threads, direct global A
// from ypm; hfr fragment residual (vector); epilogue writes hfr + next ucm.
__global__ __launch_bounds__(256) void k_glu_mfma(
    const __hip_bfloat16* __restrict__ yb,   // [M,256] bf16 pm
    float* __restrict__ hfr,                 // fragment-layout f32
    const __hip_bfloat16* __restrict__ wob,  // [512,256] bf16
    const float* __restrict__ bo, const float* __restrict__ lnw,
    const float* __restrict__ lnb, __hip_bfloat16* __restrict__ un)
{
    __shared__ __hip_bfloat16 lt[256 * 66];  // epilogue transpose (33.8 KB)
    __shared__ float red[4][64][2];
    int tid = threadIdx.x;
    int w = tid >> 6, l = tid & 63, l15 = l & 15, l4 = l >> 4;
    int m0 = blockIdx.x * 64;
    int nv = w * 64;

    // residual prefetch: 2 fragment chunks (mi=0,1), 8 x f32x4, contiguous
    f32x4 hres[2][2][4];                     // [mi][sub][nj]
    #pragma unroll
    for (int mi = 0; mi < 2; mi++) {
        const f32x4* hp = (const f32x4*)(hfr + (size_t)m0 * 256
                                         + ((size_t)((mi * 4 + w) * 64 + l)) * 32);
        #pragma unroll
        for (int sub = 0; sub < 2; sub++)
            #pragma unroll
            for (int nj = 0; nj < 4; nj++) hres[mi][sub][nj] = hp[sub * 4 + nj];
    }

    f32x4 accv[4][4], accg[4][4];
    #pragma unroll
    for (int m4 = 0; m4 < 4; m4++)
        #pragma unroll
        for (int nj = 0; nj < 4; nj++) { accv[m4][nj] = (f32x4)0.f; accg[m4][nj] = (f32x4)0.f; }

    #pragma unroll 2
    for (int ks = 0; ks < 8; ks++) {
        int k0 = ks * 32 + l4 * 8;
        bf16x8 a[4];
        #pragma unroll
        for (int m4 = 0; m4 < 4; m4++)
            a[m4] = *(const bf16x8*)(yb + (size_t)(m0 + m4 * 16 + l15) * H_ + k0);
        #pragma unroll
        for (int nj = 0; nj < 4; nj++) {
            bf16x8 bv = *(const bf16x8*)(wob + (size_t)(nv + nj * 16 + l15) * H_ + k0);
            bf16x8 bg = *(const bf16x8*)(wob + (size_t)(256 + nv + nj * 16 + l15) * H_ + k0);
            #pragma unroll
            for (int m4 = 0; m4 < 4; m4++) {
                accv[m4][nj] = __builtin_amdgcn_mfma_f32_16x16x32_bf16(a[m4], bv, accv[m4][nj], 0, 0, 0);
                accg[m4][nj] = __builtin_amdgcn_mfma_f32_16x16x32_bf16(a[m4], bg, accg[m4][nj], 0, 0, 0);
            }
        }
    }

    float bov[4], bog[4], lw[4], lb[4];
    #pragma unroll
    for (int nj = 0; nj < 4; nj++) {
        int cn = nv + nj * 16 + l15;
        bov[nj] = bo[cn]; bog[nj] = bo[256 + cn];
        lw[nj] = lnw[cn]; lb[nj] = lnb[cn];
    }
    #pragma unroll
    for (int m4 = 0; m4 < 4; m4++) {
        #pragma unroll
        for (int r = 0; r < 4; r++) {
            int lr = m4 * 16 + l4 * 4 + r;
            float s = 0.f, ss = 0.f;
            #pragma unroll
            for (int nj = 0; nj < 4; nj++) {
                float uv = accv[m4][nj][r] + bov[nj];
                float ug = accg[m4][nj][r] + bog[nj];
                float z = uv / (1.f + __expf(-ug));
                float v = z + hres[m4 >> 1][m4 & 1][nj][r];
                accv[m4][nj][r] = v;
                s += v; ss += v * v;
            }
            #pragma unroll
            for (int off = 1; off < 16; off <<= 1) {
                s  += __shfl_xor(s, off);
                ss += __shfl_xor(ss, off);
            }
            if (l15 == 0) { red[w][lr][0] = s; red[w][lr][1] = ss; }
        }
    }
    __syncthreads();
    #pragma unroll
    for (int m4 = 0; m4 < 4; m4++) {
        #pragma unroll
        for (int r = 0; r < 4; r++) {
            int lr = m4 * 16 + l4 * 4 + r;
            float s  = red[0][lr][0] + red[1][lr][0] + red[2][lr][0] + red[3][lr][0];
            float ss = red[0][lr][1] + red[1][lr][1] + red[2][lr][1] + red[3][lr][1];
            float mu = s * (1.f / 256.f);
            float var = ss * (1.f / 256.f) - mu * mu;
            float rstd = rsqrtf(var + 1e-5f);
            #pragma unroll
            for (int nj = 0; nj < 4; nj++) {
                int cn = nv + nj * 16 + l15;
                float val = (accv[m4][nj][r] - mu) * rstd * lw[nj] + lb[nj];
                accv[m4][nj][r] = val;
                lt[cn * 66 + lr] = __float2bfloat16(val);
            }
        }
    }
    // hfr writes: vectorized, fragment-contiguous
    #pragma unroll
    for (int mi = 0; mi < 2; mi++) {
        f32x4* hp = (f32x4*)(hfr + (size_t)m0 * 256
                             + ((size_t)((mi * 4 + w) * 64 + l)) * 32);
        #pragma unroll
        for (int sub = 0; sub < 2; sub++)
            #pragma unroll
            for (int nj = 0; nj < 4; nj++)
                hp[sub * 4 + nj] = accv[mi * 2 + sub][nj];
    }
    __syncthreads();
    {   // ucm write: thread = channel, 64 positions
        #pragma unroll
        for (int q = 0; q < 8; q++)
            *(short8*)(un + (size_t)tid * M_ + m0 + q * 8)
                = *(short8*)&lt[tid * 66 + q * 8];
    }
}

// ---------------------------------------------------------------------------
// decoder: reads hfr (fragment layout) via LDS unscramble; 64-pos tiles
__global__ __launch_bounds__(256) void k_decoder(const float* __restrict__ hfr,
    const float* __restrict__ out_W, const float* __restrict__ out_b,
    float* __restrict__ out)
{
    __shared__ float hs[64][260];
    __shared__ float wl[10][260];
    int m0 = blockIdx.x * 64;
    int tid = threadIdx.x;
    #pragma unroll
    for (int half = 0; half < 2; half++) {
        int cid = half * 256 + tid;          // tid32 chunk id
        int cw = cid >> 6, cl = cid & 63;
        int cmi = cw >> 2, cnq = cw & 3, cl4 = cl >> 4, cl15 = cl & 15;
        const f32x4* src = (const f32x4*)(hfr + (size_t)m0 * 256 + (size_t)cid * 32);
        #pragma unroll
        for (int sub = 0; sub < 2; sub++)
            #pragma unroll
            for (int nj = 0; nj < 4; nj++) {
                f32x4 v = src[sub * 4 + nj];
                int row = cmi * 32 + sub * 16 + cl4 * 4;
                int col = cnq * 64 + nj * 16 + cl15;
                hs[row][col] = v[0]; hs[row + 1][col] = v[1];
                hs[row + 2][col] = v[2]; hs[row + 3][col] = v[3];
            }
    }
    for (int q = tid; q < 640; q += 256) {
        int r = q / 64, k4 = q % 64;
        *(float4*)&wl[r][k4 * 4] = ((const float4*)out_W)[q];
    }
    __syncthreads();
    int slot = tid & 15;
    if (slot < DOUT) {
        #pragma unroll
        for (int pass = 0; pass < 4; pass++) {
            int pl = pass * 16 + (tid >> 4);
            float a0 = 0.f, a1 = 0.f, a2 = 0.f, a3 = 0.f;
            #pragma unroll 8
            for (int k = 0; k < 256; k += 4) {
                a0 = fmaf(hs[pl][k + 0], wl[slot][k + 0], a0);
                a1 = fmaf(hs[pl][k + 1], wl[slot][k + 1], a1);
                a2 = fmaf(hs[pl][k + 2], wl[slot][k + 2], a2);
                a3 = fmaf(hs[pl][k + 3], wl[slot][k + 3], a3);
            }
            out[(size_t)(m0 + pl) * DOUT + slot] = (a0 + a1) + (a2 + a3) + out_b[slot];
        }
    }
}

// ---------------------------------------------------------------------------
extern "C" void kernel_launch(void* const* d_in, const int* in_sizes, int n_in,
                              void* d_out, int out_size, void* d_ws, size_t ws_size,
                              hipStream_t stream)
{
    (void)in_sizes; (void)n_in; (void)out_size; (void)ws_size;
    const float* x        = (const float*)d_in[0];
    const float* enc_W    = (const float*)d_in[1];
    const float* enc_b    = (const float*)d_in[2];
    const float* log_dt   = (const float*)d_in[3];
    const float* log_A_re = (const float*)d_in[4];
    const float* A_im     = (const float*)d_in[5];
    const float* C_re     = (const float*)d_in[6];
    const float* C_im     = (const float*)d_in[7];
    const float* Dp       = (const float*)d_in[8];
    const float* Wo       = (const float*)d_in[9];
    const float* bo       = (const float*)d_in[10];
    const float* lnw      = (const float*)d_in[11];
    const float* lnb      = (const float*)d_in[12];
    const float* out_W    = (const float*)d_in[13];
    const float* out_b    = (const float*)d_in[14];
    float* ws = (float*)d_ws;
    float* hfr = ws + OFF_H;
    __hip_bfloat16* ucm = (__hip_bfloat16*)(ws + OFF_UCM);
    __hip_bfloat16* ycm = (__hip_bfloat16*)(ws + OFF_YCM);
    __hip_bfloat16* ypm = (__hip_bfloat16*)(ws + OFF_YPM);
    __hip_bfloat16* mt = (__hip_bfloat16*)(ws + OFF_MT);
    __hip_bfloat16* mw = (__hip_bfloat16*)(ws + OFF_MW);
    __hip_bfloat16* mv = (__hip_bfloat16*)(ws + OFF_MV);
    __hip_bfloat16* wob = (__hip_bfloat16*)(ws + OFF_WOB);

    k_params<<<NL_ * H_ * N2_ / 256, 256, 0, stream>>>(log_dt, log_A_re, A_im, C_re, C_im, ws);
    dim3 tb(32, 8);
    k_transpose<<<dim3(DIN / 32, H_ / 32), tb, 0, stream>>>(enc_W, ws + OFF_EWT, H_, DIN);
    k_wcvt<<<(NL_ * 2 * H_ * H_ / 4 + 255) / 256, 256, 0, stream>>>(Wo, wob, NL_ * 2 * H_ * H_ / 4);
    k_encoder<<<M_ / 32, 256, 0, stream>>>(x, ws + OFF_EWT, enc_b, hfr, ucm);
    for (int i = 0; i < NL_; i++) {
        k_mats<<<H_, 256, 0, stream>>>(ws, i, mt, mw, mv);
        k_ssm<<<H_ * B_, 256, 0, stream>>>(ucm, mt, mw, mv, ws, i, Dp, ycm);
        k_y2pm<<<dim3(M_ / 64, H_ / 64), 256, 0, stream>>>(ycm, ypm);
        k_glu_mfma<<<M_ / 64, 256, 0, stream>>>(ypm, hfr,
            wob + (size_t)i * 2 * H_ * H_, bo + (size_t)i * 2 * H_,
            lnw + (size_t)i * H_, lnb + (size_t)i * H_, ucm);
    }
    k_decoder<<<M_ / 64, 256, 0, stream>>>(hfr, out_W, out_b, (float*)d_out);
}

// Round 10
// 519.366 us; speedup vs baseline: 1.0020x; 1.0020x over previous
//
#include <hip/hip_runtime.h>
#include <hip/hip_bf16.h>

// ---------------------------------------------------------------------------
// S4D stack, MFMA everywhere:
// encoder GEMM(+cm,+hfr) -> 4x[ mats; fused SSM (u->LDS swz, state MFMA +
//   LDS scan + Toeplitz conv MFMA); y2pm; GLU MFMA + LN (BM=32, direct A,
//   hfr residual, writes next ucm) ] -> decoder (reads hfr).
// hfr: f32 fragment-contiguous on 64-row groups: chunk tid32=(mi*4+nq)*64+l:
//   [sub(2)][nj(4)][r(4)] -> row=mi*32+sub*16+(l>>4)*4+r, col=nq*64+nj*16+(l&15)
// ---------------------------------------------------------------------------

constexpr int B_ = 4, L_ = 8192, DIN = 64, H_ = 256, N2_ = 32, NL_ = 4, DOUT = 10;
constexpr int LC = 64, CHK = L_ / LC;     // 128 chunks/batch
constexpr int GCH = B_ * CHK;             // 512 global chunks
constexpr int M_ = B_ * L_;               // 32768 positions

// ws layout in float slots
constexpr size_t OFF_H    = 0;                         // f32 hfr [M*256]
constexpr size_t OFF_WOB  = 8388608;                   // bf16 Wo NL*512*256
constexpr size_t OFF_PW   = 8650752;                   // (legacy)
constexpr size_t OFF_PCT  = 8716288;                   // f32 Ct2 pairs
constexpr size_t OFF_PWLC = 8781824;                   // f32 w^64 pairs
constexpr size_t OFF_PZ   = 8847360;                   // f32 z=dtA pairs
constexpr size_t OFF_EWT  = 8912896;                   // f32 enc W^T
constexpr size_t OFF_UCM  = 8929280;                   // bf16 [H][M] u cm
constexpr size_t OFF_YCM  = 13123584;                  // bf16 [H][M] y cm
constexpr size_t OFF_YPM  = 17317888;                  // bf16 [M][H] y pm
constexpr size_t OFF_MT   = 21512192;                  // bf16 Ttr [H][64][64]
constexpr size_t OFF_MW   = 22036480;                  // bf16 Wtr
constexpr size_t OFF_MV   = 22560768;                  // bf16 Vtr
// end 23085056 slots = 92.3 MB

typedef short bf16x8 __attribute__((ext_vector_type(8)));
typedef short short8 __attribute__((ext_vector_type(8)));
typedef float f32x4  __attribute__((ext_vector_type(4)));

// ---------------------------------------------------------------------------
__global__ __launch_bounds__(256) void k_params(
    const float* __restrict__ log_dt, const float* __restrict__ log_A_re,
    const float* __restrict__ A_im, const float* __restrict__ C_re,
    const float* __restrict__ C_im, float* __restrict__ ws)
{
    int idx = blockIdx.x * 256 + threadIdx.x;     // over NL*H*N2
    if (idx >= NL_ * H_ * N2_) return;
    int i  = idx / (H_ * N2_);
    int hh = (idx / N2_) % H_;
    float dt  = expf(log_dt[i * H_ + hh]);
    float Are = -expf(log_A_re[idx]);
    float Aim = A_im[idx];
    float zre = dt * Are, zim = dt * Aim;
    float er  = expf(zre);
    float wre = er * cosf(zim), wim = er * sinf(zim);
    float d   = Are * Are + Aim * Aim;
    float nre = wre - 1.f, nim = wim;
    float qre = (nre * Are + nim * Aim) / d;
    float qim = (nim * Are - nre * Aim) / d;
    float cr = C_re[idx], ci = C_im[idx];
    float ctre = cr * qre - ci * qim;
    float ctim = cr * qim + ci * qre;
    float er2 = expf(zre * (float)LC);
    float wlre = er2 * cosf(zim * (float)LC);
    float wlim = er2 * sinf(zim * (float)LC);
    ((float2*)(ws + OFF_PW))[idx]   = make_float2(wre, wim);
    ((float2*)(ws + OFF_PCT))[idx]  = make_float2(2.f * ctre, 2.f * ctim);
    ((float2*)(ws + OFF_PWLC))[idx] = make_float2(wlre, wlim);
    ((float2*)(ws + OFF_PZ))[idx]   = make_float2(zre, zim);
}

// ---------------------------------------------------------------------------
// per-channel bf16 matrices: Ttr[t][j]=k[t-j], Wtr[m][j], Vtr[t][m]
__global__ __launch_bounds__(256) void k_mats(const float* __restrict__ ws,
    int layer, __hip_bfloat16* __restrict__ mt, __hip_bfloat16* __restrict__ mw,
    __hip_bfloat16* __restrict__ mv)
{
    int h = blockIdx.x, tid = threadIdx.x;
    __shared__ float zre[32], zim[32], ctr[32], cti[32], kv[64];
    if (tid < 32) {
        float2 z = ((const float2*)(ws + OFF_PZ))[(size_t)layer*H_*N2_ + h*N2_ + tid];
        float2 c = ((const float2*)(ws + OFF_PCT))[(size_t)layer*H_*N2_ + h*N2_ + tid];
        zre[tid] = z.x; zim[tid] = z.y; ctr[tid] = c.x; cti[tid] = c.y;
    }
    __syncthreads();
    if (tid < 64) {
        float d = (float)tid, acc = 0.f;
        for (int n = 0; n < 32; n++) {
            float er = expf(zre[n] * d);
            float co = cosf(zim[n] * d), si = sinf(zim[n] * d);
            acc += er * (ctr[n] * co - cti[n] * si);
        }
        kv[tid] = acc;
    }
    __syncthreads();
    {   // Ttr
        int t = tid >> 2, j0 = (tid & 3) * 16;
        alignas(16) __hip_bfloat16 row[16];
        #pragma unroll
        for (int jj = 0; jj < 16; jj++) {
            int j = j0 + jj;
            row[jj] = __float2bfloat16(j <= t ? kv[t - j] : 0.f);
        }
        *(short8*)(mt + (size_t)h*4096 + t*64 + j0)     = *(short8*)&row[0];
        *(short8*)(mt + (size_t)h*4096 + t*64 + j0 + 8) = *(short8*)&row[8];
    }
    {   // Wtr
        int n = tid >> 3, j0 = (tid & 7) * 8;
        alignas(16) __hip_bfloat16 rre[8], rim[8];
        #pragma unroll
        for (int jj = 0; jj < 8; jj++) {
            float e = (float)(63 - (j0 + jj));
            float er = expf(zre[n] * e);
            rre[jj] = __float2bfloat16(er * cosf(zim[n] * e));
            rim[jj] = __float2bfloat16(er * sinf(zim[n] * e));
        }
        *(short8*)(mw + (size_t)h*4096 + (2*n)*64 + j0)   = *(short8*)&rre[0];
        *(short8*)(mw + (size_t)h*4096 + (2*n+1)*64 + j0) = *(short8*)&rim[0];
    }
    {   // Vtr
        int t = tid >> 2, n0 = (tid & 3) * 8;
        float e = (float)(t + 1);
        alignas(16) __hip_bfloat16 row[16];
        #pragma unroll
        for (int k = 0; k < 8; k++) {
            int n = n0 + k;
            float er = expf(zre[n] * e);
            float wr = er * cosf(zim[n] * e), wi = er * sinf(zim[n] * e);
            row[2*k]   = __float2bfloat16(ctr[n]*wr - cti[n]*wi);
            row[2*k+1] = __float2bfloat16(-(ctr[n]*wi + cti[n]*wr));
        }
        *(short8*)(mv + (size_t)h*4096 + t*64 + 2*n0)     = *(short8*)&row[0];
        *(short8*)(mv + (size_t)h*4096 + t*64 + 2*n0 + 8) = *(short8*)&row[8];
    }
}

// ---------------------------------------------------------------------------
__global__ __launch_bounds__(256) void k_transpose(const float* __restrict__ src,
    float* __restrict__ dst, int R, int Cc)
{
    __shared__ float t[32][33];
    int x = blockIdx.x * 32 + threadIdx.x;
    #pragma unroll
    for (int i = 0; i < 4; i++) {
        int yy = blockIdx.y * 32 + threadIdx.y + i * 8;
        if (x < Cc && yy < R) t[threadIdx.y + i * 8][threadIdx.x] = src[(size_t)yy * Cc + x];
    }
    __syncthreads();
    int xo = blockIdx.y * 32 + threadIdx.x;
    #pragma unroll
    for (int i = 0; i < 4; i++) {
        int yo = blockIdx.x * 32 + threadIdx.y + i * 8;
        if (xo < R && yo < Cc) dst[(size_t)yo * R + xo] = t[threadIdx.x][threadIdx.y + i * 8];
    }
}

// ---------------------------------------------------------------------------
__global__ __launch_bounds__(256) void k_wcvt(const float* __restrict__ src,
    __hip_bfloat16* __restrict__ dst, int n4)
{
    int i = blockIdx.x * 256 + threadIdx.x;
    if (i >= n4) return;
    float4 v = ((const float4*)src)[i];
    union { __hip_bfloat16 b[4]; uint2 u; } o;
    o.b[0] = __float2bfloat16(v.x); o.b[1] = __float2bfloat16(v.y);
    o.b[2] = __float2bfloat16(v.z); o.b[3] = __float2bfloat16(v.w);
    ((uint2*)dst)[i] = o.u;
}

// ---------------------------------------------------------------------------
// encoder: h = x @ encWT + b; writes hfr (fragment layout f32) + ucm bf16 cm
__global__ __launch_bounds__(256) void k_encoder(const float* __restrict__ x,
    const float* __restrict__ encWT, const float* __restrict__ enc_b,
    float* __restrict__ hfr, __hip_bfloat16* __restrict__ ucm)
{
    __shared__ float As[DIN][36];
    __shared__ float Bs[32][268];          // B-tiles; later f32 stage [32 pos][256 ch]
    int m0e = blockIdx.x * 32;
    int tid = threadIdx.x;
    const float4* x4 = (const float4*)x;
    #pragma unroll
    for (int q = 0; q < 2; q++) {
        int f = tid * 2 + q;
        int row = f >> 4, kq = f & 15;
        float4 v = x4[(size_t)(m0e + row) * 16 + kq];
        As[kq * 4 + 0][row] = v.x; As[kq * 4 + 1][row] = v.y;
        As[kq * 4 + 2][row] = v.z; As[kq * 4 + 3][row] = v.w;
    }
    int tx = tid & 31, ty = tid >> 5;
    float acc[4][8];
    #pragma unroll
    for (int p = 0; p < 4; p++)
        #pragma unroll
        for (int j = 0; j < 8; j++) acc[p][j] = 0.f;
    const float4* w4 = (const float4*)encWT;
    for (int ks = 0; ks < 2; ks++) {
        __syncthreads();
        #pragma unroll
        for (int it = 0; it < 8; it++) {
            int q = it * 256 + tid;
            int row = q >> 6, c4 = q & 63;
            *(float4*)&Bs[row][c4 * 4] = w4[ks * 2048 + q];
        }
        __syncthreads();
        #pragma unroll 8
        for (int kk = 0; kk < 32; kk++) {
            int k = ks * 32 + kk;
            float4 a  = *(const float4*)&As[k][ty * 4];
            float4 b0 = *(const float4*)&Bs[kk][tx * 4];
            float4 b1 = *(const float4*)&Bs[kk][128 + tx * 4];
            float av[4] = {a.x, a.y, a.z, a.w};
            float bv[8] = {b0.x, b0.y, b0.z, b0.w, b1.x, b1.y, b1.z, b1.w};
            #pragma unroll
            for (int p = 0; p < 4; p++)
                #pragma unroll
                for (int j = 0; j < 8; j++)
                    acc[p][j] = fmaf(av[p], bv[j], acc[p][j]);
        }
    }
    float4 eb0 = *(const float4*)&enc_b[tx * 4];
    float4 eb1 = *(const float4*)&enc_b[128 + tx * 4];
    float ebv[8] = {eb0.x, eb0.y, eb0.z, eb0.w, eb1.x, eb1.y, eb1.z, eb1.w};
    __syncthreads();                       // Bs dead -> f32 stage st2[pl][ch]
    #pragma unroll
    for (int p = 0; p < 4; p++) {
        int pl = ty * 4 + p;
        #pragma unroll
        for (int j = 0; j < 4; j++) Bs[pl][tx * 4 + j]       = acc[p][j] + ebv[j];
        #pragma unroll
        for (int j = 0; j < 4; j++) Bs[pl][128 + tx * 4 + j] = acc[p][j + 4] + ebv[j + 4];
    }
    __syncthreads();
    // hfr write: fragment threads, 32 contiguous f32 each
    {
        size_t m0 = (size_t)(m0e & ~63);
        int mi = (m0e >> 5) & 1;
        int nq = tid >> 6, l = tid & 63, l4 = l >> 4, l15 = l & 15;
        int tid32 = (mi * 4 + nq) * 64 + l;
        float* dst = hfr + m0 * 256 + (size_t)tid32 * 32;
        #pragma unroll
        for (int sub = 0; sub < 2; sub++)
            #pragma unroll
            for (int nj = 0; nj < 4; nj++) {
                int pl = sub * 16 + l4 * 4;
                int cn = nq * 64 + nj * 16 + l15;
                float4 o = make_float4(Bs[pl][cn], Bs[pl + 1][cn], Bs[pl + 2][cn], Bs[pl + 3][cn]);
                *(float4*)(dst + sub * 16 + nj * 4) = o;
            }
    }
    // ucm write: thread = channel
    {
        alignas(16) __hip_bfloat16 row[32];
        #pragma unroll
        for (int pl = 0; pl < 32; pl++) row[pl] = __float2bfloat16(Bs[pl][tid]);
        #pragma unroll
        for (int q = 0; q < 4; q++)
            *(short8*)(ucm + (size_t)tid * M_ + m0e + q * 8) = *(short8*)&row[q * 8];
    }
}

// ---------------------------------------------------------------------------
// FUSED SSM: block = (channel, batch). u staged in XOR-swizzled LDS.
// Phase1: chunk-state MFMA -> swz LDS. Phase2: serial scan. Phase3: conv MFMA.
// swizzle: elem e within chunk c lives at c*64 + (e ^ ((c&7)<<3))
__global__ __launch_bounds__(256) void k_ssm(const __hip_bfloat16* __restrict__ ucm,
    const __hip_bfloat16* __restrict__ mt, const __hip_bfloat16* __restrict__ mw,
    const __hip_bfloat16* __restrict__ mv, const float* __restrict__ ws, int layer,
    const float* __restrict__ Dp, __hip_bfloat16* __restrict__ ycm)
{
    __shared__ __hip_bfloat16 ulds[L_];       // 16 KB swizzled u
    __shared__ __hip_bfloat16 st[CHK * 64];   // 16 KB swizzled states
    int h = blockIdx.x >> 2, b = blockIdx.x & 3;
    int tid = threadIdx.x, w = tid >> 6, l = tid & 63, l15 = l & 15, l4 = l >> 4;
    const __hip_bfloat16* ub = ucm + (size_t)h * M_ + (size_t)b * L_;
    // ---- stage u -> swizzled LDS (coalesced: 256 thr x 16B contiguous per it)
    #pragma unroll
    for (int it = 0; it < 4; it++) {
        int e0 = it * 2048 + tid * 8;
        short8 v = *(const short8*)(ub + e0);
        int c = e0 >> 6, e = e0 & 63;
        *(short8*)&ulds[c * 64 + (e ^ ((c & 7) << 3))] = v;
    }
    __syncthreads();
    // ---- phase 1: states S[g][m] = sum_j Wtr[m][j] u[g*64+j]
    {
        const __hip_bfloat16* bbase = mw + (size_t)h * 4096 + l15 * 64 + l4 * 8;
        #pragma unroll
        for (int half = 0; half < 2; half++) {
            int g0 = (w + half * 4) * 16;
            int ca = g0 + l15;
            f32x4 acc[4];
            #pragma unroll
            for (int nj = 0; nj < 4; nj++) acc[nj] = (f32x4)0.f;
            #pragma unroll
            for (int ks = 0; ks < 2; ks++) {
                int e = l4 * 8 + ks * 32;
                bf16x8 a = *(const bf16x8*)&ulds[ca * 64 + (e ^ ((ca & 7) << 3))];
                #pragma unroll
                for (int nj = 0; nj < 4; nj++) {
                    bf16x8 bb = *(const bf16x8*)(bbase + nj * 16 * 64 + ks * 32);
                    acc[nj] = __builtin_amdgcn_mfma_f32_16x16x32_bf16(a, bb, acc[nj], 0, 0, 0);
                }
            }
            #pragma unroll
            for (int nj = 0; nj < 4; nj++)
                #pragma unroll
                for (int r = 0; r < 4; r++) {
                    int c = g0 + l4 * 4 + r, e = nj * 16 + l15;
                    st[c * 64 + (e ^ ((c & 7) << 3))] = __float2bfloat16(acc[nj][r]);
                }
        }
    }
    __syncthreads();
    // ---- phase 2: serial scan over 128 chunks (32 threads)
    if (tid < 32) {
        int n = tid;
        float2 wl = ((const float2*)(ws + OFF_PWLC))[(size_t)layer * H_ * N2_ + h * 32 + n];
        float ar = 0.f, ai = 0.f;
        for (int c = 0; c < CHK; c++) {
            __hip_bfloat162* p = (__hip_bfloat162*)&st[c * 64 + ((2 * n) ^ ((c & 7) << 3))];
            float2 v = __bfloat1622float2(*p);
            *p = __float22bfloat162_rn(make_float2(ar, ai));
            float tr = fmaf(wl.x, ar, v.x); tr = fmaf(-wl.y, ai, tr);
            float ti = fmaf(wl.x, ai, v.y); ti = fmaf(wl.y, ar, ti);
            ar = tr; ai = ti;
        }
    }
    __syncthreads();
    // ---- phase 3: conv + carry + D-skip + GELU
    {
        const __hip_bfloat16* bt = mt + (size_t)h * 4096 + l15 * 64 + l4 * 8;
        const __hip_bfloat16* bv = mv + (size_t)h * 4096 + l15 * 64 + l4 * 8;
        float Dh = Dp[layer * H_ + h];
        __hip_bfloat16* yb = ycm + (size_t)h * M_ + (size_t)b * L_;
        #pragma unroll
        for (int half = 0; half < 2; half++) {
            int g0 = (w + half * 4) * 16;
            int ca = g0 + l15;
            f32x4 acc[4];
            #pragma unroll
            for (int nj = 0; nj < 4; nj++) acc[nj] = (f32x4)0.f;
            #pragma unroll
            for (int ks = 0; ks < 2; ks++) {
                int e = l4 * 8 + ks * 32;
                bf16x8 a = *(const bf16x8*)&ulds[ca * 64 + (e ^ ((ca & 7) << 3))];
                #pragma unroll
                for (int nj = 0; nj < 4; nj++) {
                    bf16x8 bb = *(const bf16x8*)(bt + nj * 16 * 64 + ks * 32);
                    acc[nj] = __builtin_amdgcn_mfma_f32_16x16x32_bf16(a, bb, acc[nj], 0, 0, 0);
                }
            }
            #pragma unroll
            for (int ks = 0; ks < 2; ks++) {
                int e = l4 * 8 + ks * 32;
                bf16x8 a = *(const bf16x8*)&st[ca * 64 + (e ^ ((ca & 7) << 3))];
                #pragma unroll
                for (int nj = 0; nj < 4; nj++) {
                    bf16x8 bb = *(const bf16x8*)(bv + nj * 16 * 64 + ks * 32);
                    acc[nj] = __builtin_amdgcn_mfma_f32_16x16x32_bf16(a, bb, acc[nj], 0, 0, 0);
                }
            }
            #pragma unroll
            for (int nj = 0; nj < 4; nj++)
                #pragma unroll
                for (int r = 0; r < 4; r++) {
                    int g = g0 + l4 * 4 + r;
                    int e = nj * 16 + l15;
                    float uv = __bfloat162float(ulds[g * 64 + (e ^ ((g & 7) << 3))]);
                    float v = fmaf(Dh, uv, acc[nj][r]);
                    float gg = 0.7978845608028654f * fmaf(0.044715f * v, v * v, v);
                    float yv = v / (1.f + __expf(-2.f * gg));
                    yb[(size_t)g * 64 + nj * 16 + l15] = __float2bfloat16(yv);
                }
        }
    }
}

// ---------------------------------------------------------------------------
// y_cm -> y_pm transpose
__global__ __launch_bounds__(256) void k_y2pm(const __hip_bfloat16* __restrict__ ycm,
    __hip_bfloat16* __restrict__ ypm)
{
    __shared__ __hip_bfloat16 lds[64][68];
    int pos0 = blockIdx.x * 64, ch0 = blockIdx.y * 64;
    int tid = threadIdx.x;
    int ch = tid >> 2, p0 = (tid & 3) * 16;
    const __hip_bfloat16* src = ycm + (size_t)(ch0 + ch) * M_ + pos0 + p0;
    #pragma unroll
    for (int k = 0; k < 2; k++)
        *(short8*)&lds[ch][p0 + k*8] = *(const short8*)(src + k*8);
    __syncthreads();
    int pp = tid >> 2, c0 = (tid & 3) * 16;
    alignas(16) __hip_bfloat16 row[16];
    #pragma unroll
    for (int k = 0; k < 16; k++) row[k] = lds[c0 + k][pp];
    size_t base = (size_t)(pos0 + pp) * H_ + ch0 + c0;
    *(short8*)(ypm + base)     = *(short8*)&row[0];
    *(short8*)(ypm + base + 8) = *(short8*)&row[8];
}

// ---------------------------------------------------------------------------
// fused MFMA GLU+LN v7: BM=32, grid 1024, 256 threads (4 waves = col quarters).
// Direct global A from ypm; hres loaded post-K-loop; fragment hfr r/w;
// epilogue writes hfr + next-layer ucm via lt LDS transpose.
__global__ __launch_bounds__(256) void k_glu_mfma(
    const __hip_bfloat16* __restrict__ yb,   // [M,256] bf16 pm
    float* __restrict__ hfr,                 // fragment-layout f32
    const __hip_bfloat16* __restrict__ wob,  // [512,256] bf16
    const float* __restrict__ bo, const float* __restrict__ lnw,
    const float* __restrict__ lnb, __hip_bfloat16* __restrict__ un)
{
    __shared__ __hip_bfloat16 lt[256 * 34];  // epilogue transpose (17.4 KB)
    __shared__ float red[4][32][2];
    int tid = threadIdx.x;
    int w = tid >> 6, l = tid & 63, l15 = l & 15, l4 = l >> 4;
    int m0 = blockIdx.x * 32;
    int mi = (m0 >> 5) & 1;
    int nv = w * 64;

    f32x4 accv[2][4], accg[2][4];
    #pragma unroll
    for (int sub = 0; sub < 2; sub++)
        #pragma unroll
        for (int nj = 0; nj < 4; nj++) { accv[sub][nj] = (f32x4)0.f; accg[sub][nj] = (f32x4)0.f; }

    #pragma unroll 2
    for (int ks = 0; ks < 8; ks++) {
        int k0 = ks * 32 + l4 * 8;
        bf16x8 a0 = *(const bf16x8*)(yb + (size_t)(m0 + l15) * H_ + k0);
        bf16x8 a1 = *(const bf16x8*)(yb + (size_t)(m0 + 16 + l15) * H_ + k0);
        #pragma unroll
        for (int nj = 0; nj < 4; nj++) {
            bf16x8 bv = *(const bf16x8*)(wob + (size_t)(nv + nj * 16 + l15) * H_ + k0);
            bf16x8 bg = *(const bf16x8*)(wob + (size_t)(256 + nv + nj * 16 + l15) * H_ + k0);
            accv[0][nj] = __builtin_amdgcn_mfma_f32_16x16x32_bf16(a0, bv, accv[0][nj], 0, 0, 0);
            accg[0][nj] = __builtin_amdgcn_mfma_f32_16x16x32_bf16(a0, bg, accg[0][nj], 0, 0, 0);
            accv[1][nj] = __builtin_amdgcn_mfma_f32_16x16x32_bf16(a1, bv, accv[1][nj], 0, 0, 0);
            accg[1][nj] = __builtin_amdgcn_mfma_f32_16x16x32_bf16(a1, bg, accg[1][nj], 0, 0, 0);
        }
    }

    // residual load (post-K-loop; tails overlap across the doubled wave count)
    float* hbase = hfr + (size_t)(m0 & ~63) * 256 + ((size_t)((mi * 4 + w) * 64 + l)) * 32;
    f32x4 hres[2][4];
    {
        const f32x4* hp = (const f32x4*)hbase;
        #pragma unroll
        for (int sub = 0; sub < 2; sub++)
            #pragma unroll
            for (int nj = 0; nj < 4; nj++) hres[sub][nj] = hp[sub * 4 + nj];
    }

    float bov[4], bog[4], lw[4], lb[4];
    #pragma unroll
    for (int nj = 0; nj < 4; nj++) {
        int cn = nv + nj * 16 + l15;
        bov[nj] = bo[cn]; bog[nj] = bo[256 + cn];
        lw[nj] = lnw[cn]; lb[nj] = lnb[cn];
    }
    #pragma unroll
    for (int sub = 0; sub < 2; sub++) {
        #pragma unroll
        for (int r = 0; r < 4; r++) {
            int lr = sub * 16 + l4 * 4 + r;
            float s = 0.f, ss = 0.f;
            #pragma unroll
            for (int nj = 0; nj < 4; nj++) {
                float uv = accv[sub][nj][r] + bov[nj];
                float ug = accg[sub][nj][r] + bog[nj];
                float z = uv / (1.f + __expf(-ug));
                float v = z + hres[sub][nj][r];
                accv[sub][nj][r] = v;
                s += v; ss += v * v;
            }
            #pragma unroll
            for (int off = 1; off < 16; off <<= 1) {
                s  += __shfl_xor(s, off);
                ss += __shfl_xor(ss, off);
            }
            if (l15 == 0) { red[w][lr][0] = s; red[w][lr][1] = ss; }
        }
    }
    __syncthreads();
    #pragma unroll
    for (int sub = 0; sub < 2; sub++) {
        #pragma unroll
        for (int r = 0; r < 4; r++) {
            int lr = sub * 16 + l4 * 4 + r;
            float s  = red[0][lr][0] + red[1][lr][0] + red[2][lr][0] + red[3][lr][0];
            float ss = red[0][lr][1] + red[1][lr][1] + red[2][lr][1] + red[3][lr][1];
            float mu = s * (1.f / 256.f);
            float var = ss * (1.f / 256.f) - mu * mu;
            float rstd = rsqrtf(var + 1e-5f);
            #pragma unroll
            for (int nj = 0; nj < 4; nj++) {
                int cn = nv + nj * 16 + l15;
                float val = (accv[sub][nj][r] - mu) * rstd * lw[nj] + lb[nj];
                accv[sub][nj][r] = val;
                lt[cn * 34 + lr] = __float2bfloat16(val);
            }
        }
    }
    // hfr write: vectorized, fragment-contiguous
    {
        f32x4* hp = (f32x4*)hbase;
        #pragma unroll
        for (int sub = 0; sub < 2; sub++)
            #pragma unroll
            for (int nj = 0; nj < 4; nj++)
                hp[sub * 4 + nj] = accv[sub][nj];
    }
    __syncthreads();
    {   // ucm write: thread = channel, 32 positions
        #pragma unroll
        for (int q = 0; q < 4; q++)
            *(short8*)(un + (size_t)tid * M_ + m0 + q * 8)
                = *(short8*)&lt[tid * 34 + q * 8];
    }
}

// ---------------------------------------------------------------------------
// decoder: reads hfr (fragment layout) via LDS unscramble; 64-pos tiles
__global__ __launch_bounds__(256) void k_decoder(const float* __restrict__ hfr,
    const float* __restrict__ out_W, const float* __restrict__ out_b,
    float* __restrict__ out)
{
    __shared__ float hs[64][260];
    __shared__ float wl[10][260];
    int m0 = blockIdx.x * 64;
    int tid = threadIdx.x;
    #pragma unroll
    for (int half = 0; half < 2; half++) {
        int cid = half * 256 + tid;          // tid32 chunk id
        int cw = cid >> 6, cl = cid & 63;
        int cmi = cw >> 2, cnq = cw & 3, cl4 = cl >> 4, cl15 = cl & 15;
        const f32x4* src = (const f32x4*)(hfr + (size_t)m0 * 256 + (size_t)cid * 32);
        #pragma unroll
        for (int sub = 0; sub < 2; sub++)
            #pragma unroll
            for (int nj = 0; nj < 4; nj++) {
                f32x4 v = src[sub * 4 + nj];
                int row = cmi * 32 + sub * 16 + cl4 * 4;
                int col = cnq * 64 + nj * 16 + cl15;
                hs[row][col] = v[0]; hs[row + 1][col] = v[1];
                hs[row + 2][col] = v[2]; hs[row + 3][col] = v[3];
            }
    }
    for (int q = tid; q < 640; q += 256) {
        int r = q / 64, k4 = q % 64;
        *(float4*)&wl[r][k4 * 4] = ((const float4*)out_W)[q];
    }
    __syncthreads();
    int slot = tid & 15;
    if (slot < DOUT) {
        #pragma unroll
        for (int pass = 0; pass < 4; pass++) {
            int pl = pass * 16 + (tid >> 4);
            float a0 = 0.f, a1 = 0.f, a2 = 0.f, a3 = 0.f;
            #pragma unroll 8
            for (int k = 0; k < 256; k += 4) {
                a0 = fmaf(hs[pl][k + 0], wl[slot][k + 0], a0);
                a1 = fmaf(hs[pl][k + 1], wl[slot][k + 1], a1);
                a2 = fmaf(hs[pl][k + 2], wl[slot][k + 2], a2);
                a3 = fmaf(hs[pl][k + 3], wl[slot][k + 3], a3);
            }
            out[(size_t)(m0 + pl) * DOUT + slot] = (a0 + a1) + (a2 + a3) + out_b[slot];
        }
    }
}

// ---------------------------------------------------------------------------
extern "C" void kernel_launch(void* const* d_in, const int* in_sizes, int n_in,
                              void* d_out, int out_size, void* d_ws, size_t ws_size,
                              hipStream_t stream)
{
    (void)in_sizes; (void)n_in; (void)out_size; (void)ws_size;
    const float* x        = (const float*)d_in[0];
    const float* enc_W    = (const float*)d_in[1];
    const float* enc_b    = (const float*)d_in[2];
    const float* log_dt   = (const float*)d_in[3];
    const float* log_A_re = (const float*)d_in[4];
    const float* A_im     = (const float*)d_in[5];
    const float* C_re     = (const float*)d_in[6];
    const float* C_im     = (const float*)d_in[7];
    const float* Dp       = (const float*)d_in[8];
    const float* Wo       = (const float*)d_in[9];
    const float* bo       = (const float*)d_in[10];
    const float* lnw      = (const float*)d_in[11];
    const float* lnb      = (const float*)d_in[12];
    const float* out_W    = (const float*)d_in[13];
    const float* out_b    = (const float*)d_in[14];
    float* ws = (float*)d_ws;
    float* hfr = ws + OFF_H;
    __hip_bfloat16* ucm = (__hip_bfloat16*)(ws + OFF_UCM);
    __hip_bfloat16* ycm = (__hip_bfloat16*)(ws + OFF_YCM);
    __hip_bfloat16* ypm = (__hip_bfloat16*)(ws + OFF_YPM);
    __hip_bfloat16* mt = (__hip_bfloat16*)(ws + OFF_MT);
    __hip_bfloat16* mw = (__hip_bfloat16*)(ws + OFF_MW);
    __hip_bfloat16* mv = (__hip_bfloat16*)(ws + OFF_MV);
    __hip_bfloat16* wob = (__hip_bfloat16*)(ws + OFF_WOB);

    k_params<<<NL_ * H_ * N2_ / 256, 256, 0, stream>>>(log_dt, log_A_re, A_im, C_re, C_im, ws);
    dim3 tb(32, 8);
    k_transpose<<<dim3(DIN / 32, H_ / 32), tb, 0, stream>>>(enc_W, ws + OFF_EWT, H_, DIN);
    k_wcvt<<<(NL_ * 2 * H_ * H_ / 4 + 255) / 256, 256, 0, stream>>>(Wo, wob, NL_ * 2 * H_ * H_ / 4);
    k_encoder<<<M_ / 32, 256, 0, stream>>>(x, ws + OFF_EWT, enc_b, hfr, ucm);
    for (int i = 0; i < NL_; i++) {
        k_mats<<<H_, 256, 0, stream>>>(ws, i, mt, mw, mv);
        k_ssm<<<H_ * B_, 256, 0, stream>>>(ucm, mt, mw, mv, ws, i, Dp, ycm);
        k_y2pm<<<dim3(M_ / 64, H_ / 64), 256, 0, stream>>>(ycm, ypm);
        k_glu_mfma<<<M_ / 32, 256, 0, stream>>>(ypm, hfr,
            wob + (size_t)i * 2 * H_ * H_, bo + (size_t)i * 2 * H_,
            lnw + (size_t)i * H_, lnb + (size_t)i * H_, ucm);
    }
    k_decoder<<<M_ / 64, 256, 0, stream>>>(hfr, out_W, out_b, (float*)d_out);
}

// Round 11
// 483.313 us; speedup vs baseline: 1.0767x; 1.0746x over previous
//
#include <hip/hip_runtime.h>
#include <hip/hip_bf16.h>

// ---------------------------------------------------------------------------
// S4D stack, MFMA everywhere:
// encoder GEMM(+cm,+hfr) -> 4x[ mats; fused SSM (u->LDS swz, state MFMA +
//   segmented LDS scan + Toeplitz conv MFMA); y2pm; GLU MFMA + LN (BM=32,
//   direct A, bf16 hfr residual, writes next ucm) ] -> decoder (reads hfr).
// hfr: bf16 fragment-contiguous on 64-row groups: chunk tid32=(mi*4+nq)*64+l:
//   [sub(2)][nj(4)][r(4)] -> row=mi*32+sub*16+(l>>4)*4+r, col=nq*64+nj*16+(l&15)
// ---------------------------------------------------------------------------

constexpr int B_ = 4, L_ = 8192, DIN = 64, H_ = 256, N2_ = 32, NL_ = 4, DOUT = 10;
constexpr int LC = 64, CHK = L_ / LC;     // 128 chunks/batch
constexpr int GCH = B_ * CHK;             // 512 global chunks
constexpr int M_ = B_ * L_;               // 32768 positions

// ws layout in float slots
constexpr size_t OFF_H    = 0;                         // bf16 hfr [M*256] (half used)
constexpr size_t OFF_WOB  = 8388608;                   // bf16 Wo NL*512*256
constexpr size_t OFF_PW   = 8650752;                   // (legacy)
constexpr size_t OFF_PCT  = 8716288;                   // f32 Ct2 pairs
constexpr size_t OFF_PWLC = 8781824;                   // f32 w^64 pairs
constexpr size_t OFF_PZ   = 8847360;                   // f32 z=dtA pairs
constexpr size_t OFF_EWT  = 8912896;                   // f32 enc W^T
constexpr size_t OFF_UCM  = 8929280;                   // bf16 [H][M] u cm
constexpr size_t OFF_YCM  = 13123584;                  // bf16 [H][M] y cm
constexpr size_t OFF_YPM  = 17317888;                  // bf16 [M][H] y pm
constexpr size_t OFF_MT   = 21512192;                  // bf16 Ttr [H][64][64]
constexpr size_t OFF_MW   = 22036480;                  // bf16 Wtr
constexpr size_t OFF_MV   = 22560768;                  // bf16 Vtr
// end 23085056 slots = 92.3 MB

typedef short bf16x8 __attribute__((ext_vector_type(8)));
typedef short short8 __attribute__((ext_vector_type(8)));
typedef float f32x4  __attribute__((ext_vector_type(4)));

__device__ __forceinline__ float b2f(short s) {
    union { float f; unsigned u; } c;
    c.u = ((unsigned)(unsigned short)s) << 16;
    return c.f;
}

// ---------------------------------------------------------------------------
__global__ __launch_bounds__(256) void k_params(
    const float* __restrict__ log_dt, const float* __restrict__ log_A_re,
    const float* __restrict__ A_im, const float* __restrict__ C_re,
    const float* __restrict__ C_im, float* __restrict__ ws)
{
    int idx = blockIdx.x * 256 + threadIdx.x;     // over NL*H*N2
    if (idx >= NL_ * H_ * N2_) return;
    int i  = idx / (H_ * N2_);
    int hh = (idx / N2_) % H_;
    float dt  = expf(log_dt[i * H_ + hh]);
    float Are = -expf(log_A_re[idx]);
    float Aim = A_im[idx];
    float zre = dt * Are, zim = dt * Aim;
    float er  = expf(zre);
    float wre = er * cosf(zim), wim = er * sinf(zim);
    float d   = Are * Are + Aim * Aim;
    float nre = wre - 1.f, nim = wim;
    float qre = (nre * Are + nim * Aim) / d;
    float qim = (nim * Are - nre * Aim) / d;
    float cr = C_re[idx], ci = C_im[idx];
    float ctre = cr * qre - ci * qim;
    float ctim = cr * qim + ci * qre;
    float er2 = expf(zre * (float)LC);
    float wlre = er2 * cosf(zim * (float)LC);
    float wlim = er2 * sinf(zim * (float)LC);
    ((float2*)(ws + OFF_PW))[idx]   = make_float2(wre, wim);
    ((float2*)(ws + OFF_PCT))[idx]  = make_float2(2.f * ctre, 2.f * ctim);
    ((float2*)(ws + OFF_PWLC))[idx] = make_float2(wlre, wlim);
    ((float2*)(ws + OFF_PZ))[idx]   = make_float2(zre, zim);
}

// ---------------------------------------------------------------------------
// per-channel bf16 matrices: Ttr[t][j]=k[t-j], Wtr[m][j], Vtr[t][m]
__global__ __launch_bounds__(256) void k_mats(const float* __restrict__ ws,
    int layer, __hip_bfloat16* __restrict__ mt, __hip_bfloat16* __restrict__ mw,
    __hip_bfloat16* __restrict__ mv)
{
    int h = blockIdx.x, tid = threadIdx.x;
    __shared__ float zre[32], zim[32], ctr[32], cti[32], kv[64];
    if (tid < 32) {
        float2 z = ((const float2*)(ws + OFF_PZ))[(size_t)layer*H_*N2_ + h*N2_ + tid];
        float2 c = ((const float2*)(ws + OFF_PCT))[(size_t)layer*H_*N2_ + h*N2_ + tid];
        zre[tid] = z.x; zim[tid] = z.y; ctr[tid] = c.x; cti[tid] = c.y;
    }
    __syncthreads();
    if (tid < 64) {
        float d = (float)tid, acc = 0.f;
        for (int n = 0; n < 32; n++) {
            float er = expf(zre[n] * d);
            float co = cosf(zim[n] * d), si = sinf(zim[n] * d);
            acc += er * (ctr[n] * co - cti[n] * si);
        }
        kv[tid] = acc;
    }
    __syncthreads();
    {   // Ttr
        int t = tid >> 2, j0 = (tid & 3) * 16;
        alignas(16) __hip_bfloat16 row[16];
        #pragma unroll
        for (int jj = 0; jj < 16; jj++) {
            int j = j0 + jj;
            row[jj] = __float2bfloat16(j <= t ? kv[t - j] : 0.f);
        }
        *(short8*)(mt + (size_t)h*4096 + t*64 + j0)     = *(short8*)&row[0];
        *(short8*)(mt + (size_t)h*4096 + t*64 + j0 + 8) = *(short8*)&row[8];
    }
    {   // Wtr
        int n = tid >> 3, j0 = (tid & 7) * 8;
        alignas(16) __hip_bfloat16 rre[8], rim[8];
        #pragma unroll
        for (int jj = 0; jj < 8; jj++) {
            float e = (float)(63 - (j0 + jj));
            float er = expf(zre[n] * e);
            rre[jj] = __float2bfloat16(er * cosf(zim[n] * e));
            rim[jj] = __float2bfloat16(er * sinf(zim[n] * e));
        }
        *(short8*)(mw + (size_t)h*4096 + (2*n)*64 + j0)   = *(short8*)&rre[0];
        *(short8*)(mw + (size_t)h*4096 + (2*n+1)*64 + j0) = *(short8*)&rim[0];
    }
    {   // Vtr
        int t = tid >> 2, n0 = (tid & 3) * 8;
        float e = (float)(t + 1);
        alignas(16) __hip_bfloat16 row[16];
        #pragma unroll
        for (int k = 0; k < 8; k++) {
            int n = n0 + k;
            float er = expf(zre[n] * e);
            float wr = er * cosf(zim[n] * e), wi = er * sinf(zim[n] * e);
            row[2*k]   = __float2bfloat16(ctr[n]*wr - cti[n]*wi);
            row[2*k+1] = __float2bfloat16(-(ctr[n]*wi + cti[n]*wr));
        }
        *(short8*)(mv + (size_t)h*4096 + t*64 + 2*n0)     = *(short8*)&row[0];
        *(short8*)(mv + (size_t)h*4096 + t*64 + 2*n0 + 8) = *(short8*)&row[8];
    }
}

// ---------------------------------------------------------------------------
__global__ __launch_bounds__(256) void k_transpose(const float* __restrict__ src,
    float* __restrict__ dst, int R, int Cc)
{
    __shared__ float t[32][33];
    int x = blockIdx.x * 32 + threadIdx.x;
    #pragma unroll
    for (int i = 0; i < 4; i++) {
        int yy = blockIdx.y * 32 + threadIdx.y + i * 8;
        if (x < Cc && yy < R) t[threadIdx.y + i * 8][threadIdx.x] = src[(size_t)yy * Cc + x];
    }
    __syncthreads();
    int xo = blockIdx.y * 32 + threadIdx.x;
    #pragma unroll
    for (int i = 0; i < 4; i++) {
        int yo = blockIdx.x * 32 + threadIdx.y + i * 8;
        if (xo < R && yo < Cc) dst[(size_t)yo * R + xo] = t[threadIdx.x][threadIdx.y + i * 8];
    }
}

// ---------------------------------------------------------------------------
__global__ __launch_bounds__(256) void k_wcvt(const float* __restrict__ src,
    __hip_bfloat16* __restrict__ dst, int n4)
{
    int i = blockIdx.x * 256 + threadIdx.x;
    if (i >= n4) return;
    float4 v = ((const float4*)src)[i];
    union { __hip_bfloat16 b[4]; uint2 u; } o;
    o.b[0] = __float2bfloat16(v.x); o.b[1] = __float2bfloat16(v.y);
    o.b[2] = __float2bfloat16(v.z); o.b[3] = __float2bfloat16(v.w);
    ((uint2*)dst)[i] = o.u;
}

// ---------------------------------------------------------------------------
// encoder: h = x @ encWT + b; writes hfr (bf16 fragment layout) + ucm bf16 cm
__global__ __launch_bounds__(256) void k_encoder(const float* __restrict__ x,
    const float* __restrict__ encWT, const float* __restrict__ enc_b,
    __hip_bfloat16* __restrict__ hfr, __hip_bfloat16* __restrict__ ucm)
{
    __shared__ float As[DIN][36];
    __shared__ float Bs[32][268];          // B-tiles; later f32 stage [32 pos][256 ch]
    int m0e = blockIdx.x * 32;
    int tid = threadIdx.x;
    const float4* x4 = (const float4*)x;
    #pragma unroll
    for (int q = 0; q < 2; q++) {
        int f = tid * 2 + q;
        int row = f >> 4, kq = f & 15;
        float4 v = x4[(size_t)(m0e + row) * 16 + kq];
        As[kq * 4 + 0][row] = v.x; As[kq * 4 + 1][row] = v.y;
        As[kq * 4 + 2][row] = v.z; As[kq * 4 + 3][row] = v.w;
    }
    int tx = tid & 31, ty = tid >> 5;
    float acc[4][8];
    #pragma unroll
    for (int p = 0; p < 4; p++)
        #pragma unroll
        for (int j = 0; j < 8; j++) acc[p][j] = 0.f;
    const float4* w4 = (const float4*)encWT;
    for (int ks = 0; ks < 2; ks++) {
        __syncthreads();
        #pragma unroll
        for (int it = 0; it < 8; it++) {
            int q = it * 256 + tid;
            int row = q >> 6, c4 = q & 63;
            *(float4*)&Bs[row][c4 * 4] = w4[ks * 2048 + q];
        }
        __syncthreads();
        #pragma unroll 8
        for (int kk = 0; kk < 32; kk++) {
            int k = ks * 32 + kk;
            float4 a  = *(const float4*)&As[k][ty * 4];
            float4 b0 = *(const float4*)&Bs[kk][tx * 4];
            float4 b1 = *(const float4*)&Bs[kk][128 + tx * 4];
            float av[4] = {a.x, a.y, a.z, a.w};
            float bv[8] = {b0.x, b0.y, b0.z, b0.w, b1.x, b1.y, b1.z, b1.w};
            #pragma unroll
            for (int p = 0; p < 4; p++)
                #pragma unroll
                for (int j = 0; j < 8; j++)
                    acc[p][j] = fmaf(av[p], bv[j], acc[p][j]);
        }
    }
    float4 eb0 = *(const float4*)&enc_b[tx * 4];
    float4 eb1 = *(const float4*)&enc_b[128 + tx * 4];
    float ebv[8] = {eb0.x, eb0.y, eb0.z, eb0.w, eb1.x, eb1.y, eb1.z, eb1.w};
    __syncthreads();                       // Bs dead -> f32 stage st2[pl][ch]
    #pragma unroll
    for (int p = 0; p < 4; p++) {
        int pl = ty * 4 + p;
        #pragma unroll
        for (int j = 0; j < 4; j++) Bs[pl][tx * 4 + j]       = acc[p][j] + ebv[j];
        #pragma unroll
        for (int j = 0; j < 4; j++) Bs[pl][128 + tx * 4 + j] = acc[p][j + 4] + ebv[j + 4];
    }
    __syncthreads();
    // hfr write: fragment threads, 32 contiguous bf16 each
    {
        size_t m0 = (size_t)(m0e & ~63);
        int mi = (m0e >> 5) & 1;
        int nq = tid >> 6, l = tid & 63, l4 = l >> 4, l15 = l & 15;
        int tid32 = (mi * 4 + nq) * 64 + l;
        __hip_bfloat16* dst = hfr + m0 * 256 + (size_t)tid32 * 32;
        alignas(16) __hip_bfloat16 tmp[32];
        #pragma unroll
        for (int sub = 0; sub < 2; sub++)
            #pragma unroll
            for (int nj = 0; nj < 4; nj++) {
                int pl = sub * 16 + l4 * 4;
                int cn = nq * 64 + nj * 16 + l15;
                #pragma unroll
                for (int r = 0; r < 4; r++)
                    tmp[sub * 16 + nj * 4 + r] = __float2bfloat16(Bs[pl + r][cn]);
            }
        #pragma unroll
        for (int q = 0; q < 4; q++)
            *(short8*)(dst + q * 8) = *(short8*)&tmp[q * 8];
    }
    // ucm write: thread = channel
    {
        alignas(16) __hip_bfloat16 row[32];
        #pragma unroll
        for (int pl = 0; pl < 32; pl++) row[pl] = __float2bfloat16(Bs[pl][tid]);
        #pragma unroll
        for (int q = 0; q < 4; q++)
            *(short8*)(ucm + (size_t)tid * M_ + m0e + q * 8) = *(short8*)&row[q * 8];
    }
}

// ---------------------------------------------------------------------------
// FUSED SSM: block = (channel, batch). u staged in XOR-swizzled LDS.
// Phase1: chunk-state MFMA -> swz LDS. Phase2: 8-way segmented scan (all 256
// threads). Phase3: conv MFMA + carry + GELU.
// swizzle: elem e within chunk c lives at c*64 + (e ^ ((c&7)<<3))
__global__ __launch_bounds__(256) void k_ssm(const __hip_bfloat16* __restrict__ ucm,
    const __hip_bfloat16* __restrict__ mt, const __hip_bfloat16* __restrict__ mw,
    const __hip_bfloat16* __restrict__ mv, const float* __restrict__ ws, int layer,
    const float* __restrict__ Dp, __hip_bfloat16* __restrict__ ycm)
{
    __shared__ __hip_bfloat16 ulds[L_];       // 16 KB swizzled u
    __shared__ __hip_bfloat16 st[CHK * 64];   // 16 KB swizzled states
    __shared__ float segT[8][32][2];          // 2 KB segment totals
    int h = blockIdx.x >> 2, b = blockIdx.x & 3;
    int tid = threadIdx.x, w = tid >> 6, l = tid & 63, l15 = l & 15, l4 = l >> 4;
    const __hip_bfloat16* ub = ucm + (size_t)h * M_ + (size_t)b * L_;
    // ---- stage u -> swizzled LDS (coalesced: 256 thr x 16B contiguous per it)
    #pragma unroll
    for (int it = 0; it < 4; it++) {
        int e0 = it * 2048 + tid * 8;
        short8 v = *(const short8*)(ub + e0);
        int c = e0 >> 6, e = e0 & 63;
        *(short8*)&ulds[c * 64 + (e ^ ((c & 7) << 3))] = v;
    }
    __syncthreads();
    // ---- phase 1: states S[g][m] = sum_j Wtr[m][j] u[g*64+j]
    {
        const __hip_bfloat16* bbase = mw + (size_t)h * 4096 + l15 * 64 + l4 * 8;
        #pragma unroll
        for (int half = 0; half < 2; half++) {
            int g0 = (w + half * 4) * 16;
            int ca = g0 + l15;
            f32x4 acc[4];
            #pragma unroll
            for (int nj = 0; nj < 4; nj++) acc[nj] = (f32x4)0.f;
            #pragma unroll
            for (int ks = 0; ks < 2; ks++) {
                int e = l4 * 8 + ks * 32;
                bf16x8 a = *(const bf16x8*)&ulds[ca * 64 + (e ^ ((ca & 7) << 3))];
                #pragma unroll
                for (int nj = 0; nj < 4; nj++) {
                    bf16x8 bb = *(const bf16x8*)(bbase + nj * 16 * 64 + ks * 32);
                    acc[nj] = __builtin_amdgcn_mfma_f32_16x16x32_bf16(a, bb, acc[nj], 0, 0, 0);
                }
            }
            #pragma unroll
            for (int nj = 0; nj < 4; nj++)
                #pragma unroll
                for (int r = 0; r < 4; r++) {
                    int c = g0 + l4 * 4 + r, e = nj * 16 + l15;
                    st[c * 64 + (e ^ ((c & 7) << 3))] = __float2bfloat16(acc[nj][r]);
                }
        }
    }
    __syncthreads();
    // ---- phase 2: segmented scan, 8 segments x 16 chunks, thread=(seg, n)
    {
        int s = tid >> 5, n = tid & 31;
        float2 wl = ((const float2*)(ws + OFF_PWLC))[(size_t)layer * H_ * N2_ + h * 32 + n];
        // pass A: local fold T_s = sum_j wl^{15-j} x_j
        float tr = 0.f, ti = 0.f;
        for (int j = 0; j < 16; j++) {
            int c = s * 16 + j;
            __hip_bfloat162* p = (__hip_bfloat162*)&st[c * 64 + ((2 * n) ^ ((c & 7) << 3))];
            float2 v = __bfloat1622float2(*p);
            float nr = fmaf(wl.x, tr, v.x); nr = fmaf(-wl.y, ti, nr);
            float ni = fmaf(wl.x, ti, v.y); ni = fmaf(wl.y, tr, ni);
            tr = nr; ti = ni;
        }
        segT[s][n][0] = tr; segT[s][n][1] = ti;
        __syncthreads();
        // W16 = wl^16
        float wr = wl.x, wi = wl.y;
        #pragma unroll
        for (int q = 0; q < 4; q++) {
            float nr = wr * wr - wi * wi, ni = 2.f * wr * wi;
            wr = nr; wi = ni;
        }
        // pass B: carry into segment s
        float ar = 0.f, ai = 0.f;
        for (int t = 0; t < s; t++) {
            float Tx = segT[t][n][0], Ty = segT[t][n][1];
            float nr = fmaf(wr, ar, Tx); nr = fmaf(-wi, ai, nr);
            float ni = fmaf(wr, ai, Ty); ni = fmaf(wi, ar, ni);
            ar = nr; ai = ni;
        }
        // pass C: expand within segment (st[c] <- incoming state)
        for (int j = 0; j < 16; j++) {
            int c = s * 16 + j;
            __hip_bfloat162* p = (__hip_bfloat162*)&st[c * 64 + ((2 * n) ^ ((c & 7) << 3))];
            float2 v = __bfloat1622float2(*p);
            *p = __float22bfloat162_rn(make_float2(ar, ai));
            float nr = fmaf(wl.x, ar, v.x); nr = fmaf(-wl.y, ai, nr);
            float ni = fmaf(wl.x, ai, v.y); ni = fmaf(wl.y, ar, ni);
            ar = nr; ai = ni;
        }
    }
    __syncthreads();
    // ---- phase 3: conv + carry + D-skip + GELU
    {
        const __hip_bfloat16* bt = mt + (size_t)h * 4096 + l15 * 64 + l4 * 8;
        const __hip_bfloat16* bv = mv + (size_t)h * 4096 + l15 * 64 + l4 * 8;
        float Dh = Dp[layer * H_ + h];
        __hip_bfloat16* yb = ycm + (size_t)h * M_ + (size_t)b * L_;
        #pragma unroll
        for (int half = 0; half < 2; half++) {
            int g0 = (w + half * 4) * 16;
            int ca = g0 + l15;
            f32x4 acc[4];
            #pragma unroll
            for (int nj = 0; nj < 4; nj++) acc[nj] = (f32x4)0.f;
            #pragma unroll
            for (int ks = 0; ks < 2; ks++) {
                int e = l4 * 8 + ks * 32;
                bf16x8 a = *(const bf16x8*)&ulds[ca * 64 + (e ^ ((ca & 7) << 3))];
                #pragma unroll
                for (int nj = 0; nj < 4; nj++) {
                    bf16x8 bb = *(const bf16x8*)(bt + nj * 16 * 64 + ks * 32);
                    acc[nj] = __builtin_amdgcn_mfma_f32_16x16x32_bf16(a, bb, acc[nj], 0, 0, 0);
                }
            }
            #pragma unroll
            for (int ks = 0; ks < 2; ks++) {
                int e = l4 * 8 + ks * 32;
                bf16x8 a = *(const bf16x8*)&st[ca * 64 + (e ^ ((ca & 7) << 3))];
                #pragma unroll
                for (int nj = 0; nj < 4; nj++) {
                    bf16x8 bb = *(const bf16x8*)(bv + nj * 16 * 64 + ks * 32);
                    acc[nj] = __builtin_amdgcn_mfma_f32_16x16x32_bf16(a, bb, acc[nj], 0, 0, 0);
                }
            }
            #pragma unroll
            for (int nj = 0; nj < 4; nj++)
                #pragma unroll
                for (int r = 0; r < 4; r++) {
                    int g = g0 + l4 * 4 + r;
                    int e = nj * 16 + l15;
                    float uv = __bfloat162float(ulds[g * 64 + (e ^ ((g & 7) << 3))]);
                    float v = fmaf(Dh, uv, acc[nj][r]);
                    float gg = 0.7978845608028654f * fmaf(0.044715f * v, v * v, v);
                    float yv = v / (1.f + __expf(-2.f * gg));
                    yb[(size_t)g * 64 + nj * 16 + l15] = __float2bfloat16(yv);
                }
        }
    }
}

// ---------------------------------------------------------------------------
// y_cm -> y_pm transpose
__global__ __launch_bounds__(256) void k_y2pm(const __hip_bfloat16* __restrict__ ycm,
    __hip_bfloat16* __restrict__ ypm)
{
    __shared__ __hip_bfloat16 lds[64][68];
    int pos0 = blockIdx.x * 64, ch0 = blockIdx.y * 64;
    int tid = threadIdx.x;
    int ch = tid >> 2, p0 = (tid & 3) * 16;
    const __hip_bfloat16* src = ycm + (size_t)(ch0 + ch) * M_ + pos0 + p0;
    #pragma unroll
    for (int k = 0; k < 2; k++)
        *(short8*)&lds[ch][p0 + k*8] = *(const short8*)(src + k*8);
    __syncthreads();
    int pp = tid >> 2, c0 = (tid & 3) * 16;
    alignas(16) __hip_bfloat16 row[16];
    #pragma unroll
    for (int k = 0; k < 16; k++) row[k] = lds[c0 + k][pp];
    size_t base = (size_t)(pos0 + pp) * H_ + ch0 + c0;
    *(short8*)(ypm + base)     = *(short8*)&row[0];
    *(short8*)(ypm + base + 8) = *(short8*)&row[8];
}

// ---------------------------------------------------------------------------
// fused MFMA GLU+LN v8: BM=32, grid 1024, 256 threads (4 waves = col quarters).
// Direct global A from ypm; bf16 hfr residual prefetched EARLY; epilogue
// writes bf16 hfr + next-layer ucm via lt LDS transpose.
__global__ __launch_bounds__(256) void k_glu_mfma(
    const __hip_bfloat16* __restrict__ yb,   // [M,256] bf16 pm
    __hip_bfloat16* __restrict__ hfr,        // bf16 fragment-layout
    const __hip_bfloat16* __restrict__ wob,  // [512,256] bf16
    const float* __restrict__ bo, const float* __restrict__ lnw,
    const float* __restrict__ lnb, __hip_bfloat16* __restrict__ un)
{
    __shared__ __hip_bfloat16 lt[256 * 34];  // epilogue transpose (17.4 KB)
    __shared__ float red[4][32][2];
    int tid = threadIdx.x;
    int w = tid >> 6, l = tid & 63, l15 = l & 15, l4 = l >> 4;
    int m0 = blockIdx.x * 32;
    int mi = (m0 >> 5) & 1;
    int nv = w * 64;

    // residual prefetch EARLY (64 B/thread; latency hides under the K-loop)
    __hip_bfloat16* hbase = hfr + (size_t)(m0 & ~63) * 256
                            + ((size_t)((mi * 4 + w) * 64 + l)) * 32;
    bf16x8 hraw[4];
    #pragma unroll
    for (int q = 0; q < 4; q++) hraw[q] = *(const bf16x8*)(hbase + q * 8);

    f32x4 accv[2][4], accg[2][4];
    #pragma unroll
    for (int sub = 0; sub < 2; sub++)
        #pragma unroll
        for (int nj = 0; nj < 4; nj++) { accv[sub][nj] = (f32x4)0.f; accg[sub][nj] = (f32x4)0.f; }

    #pragma unroll 2
    for (int ks = 0; ks < 8; ks++) {
        int k0 = ks * 32 + l4 * 8;
        bf16x8 a0 = *(const bf16x8*)(yb + (size_t)(m0 + l15) * H_ + k0);
        bf16x8 a1 = *(const bf16x8*)(yb + (size_t)(m0 + 16 + l15) * H_ + k0);
        #pragma unroll
        for (int nj = 0; nj < 4; nj++) {
            bf16x8 bv = *(const bf16x8*)(wob + (size_t)(nv + nj * 16 + l15) * H_ + k0);
            bf16x8 bg = *(const bf16x8*)(wob + (size_t)(256 + nv + nj * 16 + l15) * H_ + k0);
            accv[0][nj] = __builtin_amdgcn_mfma_f32_16x16x32_bf16(a0, bv, accv[0][nj], 0, 0, 0);
            accg[0][nj] = __builtin_amdgcn_mfma_f32_16x16x32_bf16(a0, bg, accg[0][nj], 0, 0, 0);
            accv[1][nj] = __builtin_amdgcn_mfma_f32_16x16x32_bf16(a1, bv, accv[1][nj], 0, 0, 0);
            accg[1][nj] = __builtin_amdgcn_mfma_f32_16x16x32_bf16(a1, bg, accg[1][nj], 0, 0, 0);
        }
    }

    float bov[4], bog[4], lw[4], lb[4];
    #pragma unroll
    for (int nj = 0; nj < 4; nj++) {
        int cn = nv + nj * 16 + l15;
        bov[nj] = bo[cn]; bog[nj] = bo[256 + cn];
        lw[nj] = lnw[cn]; lb[nj] = lnb[cn];
    }
    #pragma unroll
    for (int sub = 0; sub < 2; sub++) {
        #pragma unroll
        for (int r = 0; r < 4; r++) {
            int lr = sub * 16 + l4 * 4 + r;
            float s = 0.f, ss = 0.f;
            #pragma unroll
            for (int nj = 0; nj < 4; nj++) {
                int idx = sub * 16 + nj * 4 + r;
                float uv = accv[sub][nj][r] + bov[nj];
                float ug = accg[sub][nj][r] + bog[nj];
                float z = uv / (1.f + __expf(-ug));
                float v = z + b2f(hraw[idx >> 3][idx & 7]);
                accv[sub][nj][r] = v;
                s += v; ss += v * v;
            }
            #pragma unroll
            for (int off = 1; off < 16; off <<= 1) {
                s  += __shfl_xor(s, off);
                ss += __shfl_xor(ss, off);
            }
            if (l15 == 0) { red[w][lr][0] = s; red[w][lr][1] = ss; }
        }
    }
    __syncthreads();
    alignas(16) __hip_bfloat16 tmp[32];
    #pragma unroll
    for (int sub = 0; sub < 2; sub++) {
        #pragma unroll
        for (int r = 0; r < 4; r++) {
            int lr = sub * 16 + l4 * 4 + r;
            float s  = red[0][lr][0] + red[1][lr][0] + red[2][lr][0] + red[3][lr][0];
            float ss = red[0][lr][1] + red[1][lr][1] + red[2][lr][1] + red[3][lr][1];
            float mu = s * (1.f / 256.f);
            float var = ss * (1.f / 256.f) - mu * mu;
            float rstd = rsqrtf(var + 1e-5f);
            #pragma unroll
            for (int nj = 0; nj < 4; nj++) {
                int cn = nv + nj * 16 + l15;
                int idx = sub * 16 + nj * 4 + r;
                float val = (accv[sub][nj][r] - mu) * rstd * lw[nj] + lb[nj];
                __hip_bfloat16 bval = __float2bfloat16(val);
                tmp[idx] = bval;
                lt[cn * 34 + lr] = bval;
            }
        }
    }
    // hfr write: 64 B/thread contiguous
    #pragma unroll
    for (int q = 0; q < 4; q++)
        *(short8*)(hbase + q * 8) = *(short8*)&tmp[q * 8];
    __syncthreads();
    {   // ucm write: thread = channel, 32 positions
        #pragma unroll
        for (int q = 0; q < 4; q++)
            *(short8*)(un + (size_t)tid * M_ + m0 + q * 8)
                = *(short8*)&lt[tid * 34 + q * 8];
    }
}

// ---------------------------------------------------------------------------
// decoder: reads bf16 hfr (fragment layout) via LDS unscramble; 64-pos tiles
__global__ __launch_bounds__(256) void k_decoder(const __hip_bfloat16* __restrict__ hfr,
    const float* __restrict__ out_W, const float* __restrict__ out_b,
    float* __restrict__ out)
{
    __shared__ float hs[64][260];
    __shared__ float wl[10][260];
    int m0 = blockIdx.x * 64;
    int tid = threadIdx.x;
    #pragma unroll
    for (int half = 0; half < 2; half++) {
        int cid = half * 256 + tid;          // tid32 chunk id
        int cw = cid >> 6, cl = cid & 63;
        int cmi = cw >> 2, cnq = cw & 3, cl4 = cl >> 4, cl15 = cl & 15;
        const bf16x8* src = (const bf16x8*)(hfr + (size_t)m0 * 256 + (size_t)cid * 32);
        bf16x8 raw[4];
        #pragma unroll
        for (int q = 0; q < 4; q++) raw[q] = src[q];
        #pragma unroll
        for (int sub = 0; sub < 2; sub++)
            #pragma unroll
            for (int nj = 0; nj < 4; nj++) {
                int row = cmi * 32 + sub * 16 + cl4 * 4;
                int col = cnq * 64 + nj * 16 + cl15;
                #pragma unroll
                for (int r = 0; r < 4; r++) {
                    int idx = sub * 16 + nj * 4 + r;
                    hs[row + r][col] = b2f(raw[idx >> 3][idx & 7]);
                }
            }
    }
    for (int q = tid; q < 640; q += 256) {
        int r = q / 64, k4 = q % 64;
        *(float4*)&wl[r][k4 * 4] = ((const float4*)out_W)[q];
    }
    __syncthreads();
    int slot = tid & 15;
    if (slot < DOUT) {
        #pragma unroll
        for (int pass = 0; pass < 4; pass++) {
            int pl = pass * 16 + (tid >> 4);
            float a0 = 0.f, a1 = 0.f, a2 = 0.f, a3 = 0.f;
            #pragma unroll 8
            for (int k = 0; k < 256; k += 4) {
                a0 = fmaf(hs[pl][k + 0], wl[slot][k + 0], a0);
                a1 = fmaf(hs[pl][k + 1], wl[slot][k + 1], a1);
                a2 = fmaf(hs[pl][k + 2], wl[slot][k + 2], a2);
                a3 = fmaf(hs[pl][k + 3], wl[slot][k + 3], a3);
            }
            out[(size_t)(m0 + pl) * DOUT + slot] = (a0 + a1) + (a2 + a3) + out_b[slot];
        }
    }
}

// ---------------------------------------------------------------------------
extern "C" void kernel_launch(void* const* d_in, const int* in_sizes, int n_in,
                              void* d_out, int out_size, void* d_ws, size_t ws_size,
                              hipStream_t stream)
{
    (void)in_sizes; (void)n_in; (void)out_size; (void)ws_size;
    const float* x        = (const float*)d_in[0];
    const float* enc_W    = (const float*)d_in[1];
    const float* enc_b    = (const float*)d_in[2];
    const float* log_dt   = (const float*)d_in[3];
    const float* log_A_re = (const float*)d_in[4];
    const float* A_im     = (const float*)d_in[5];
    const float* C_re     = (const float*)d_in[6];
    const float* C_im     = (const float*)d_in[7];
    const float* Dp       = (const float*)d_in[8];
    const float* Wo       = (const float*)d_in[9];
    const float* bo       = (const float*)d_in[10];
    const float* lnw      = (const float*)d_in[11];
    const float* lnb      = (const float*)d_in[12];
    const float* out_W    = (const float*)d_in[13];
    const float* out_b    = (const float*)d_in[14];
    float* ws = (float*)d_ws;
    __hip_bfloat16* hfr = (__hip_bfloat16*)(ws + OFF_H);
    __hip_bfloat16* ucm = (__hip_bfloat16*)(ws + OFF_UCM);
    __hip_bfloat16* ycm = (__hip_bfloat16*)(ws + OFF_YCM);
    __hip_bfloat16* ypm = (__hip_bfloat16*)(ws + OFF_YPM);
    __hip_bfloat16* mt = (__hip_bfloat16*)(ws + OFF_MT);
    __hip_bfloat16* mw = (__hip_bfloat16*)(ws + OFF_MW);
    __hip_bfloat16* mv = (__hip_bfloat16*)(ws + OFF_MV);
    __hip_bfloat16* wob = (__hip_bfloat16*)(ws + OFF_WOB);

    k_params<<<NL_ * H_ * N2_ / 256, 256, 0, stream>>>(log_dt, log_A_re, A_im, C_re, C_im, ws);
    dim3 tb(32, 8);
    k_transpose<<<dim3(DIN / 32, H_ / 32), tb, 0, stream>>>(enc_W, ws + OFF_EWT, H_, DIN);
    k_wcvt<<<(NL_ * 2 * H_ * H_ / 4 + 255) / 256, 256, 0, stream>>>(Wo, wob, NL_ * 2 * H_ * H_ / 4);
    k_encoder<<<M_ / 32, 256, 0, stream>>>(x, ws + OFF_EWT, enc_b, hfr, ucm);
    for (int i = 0; i < NL_; i++) {
        k_mats<<<H_, 256, 0, stream>>>(ws, i, mt, mw, mv);
        k_ssm<<<H_ * B_, 256, 0, stream>>>(ucm, mt, mw, mv, ws, i, Dp, ycm);
        k_y2pm<<<dim3(M_ / 64, H_ / 64), 256, 0, stream>>>(ycm, ypm);
        k_glu_mfma<<<M_ / 32, 256, 0, stream>>>(ypm, hfr,
            wob + (size_t)i * 2 * H_ * H_, bo + (size_t)i * 2 * H_,
            lnw + (size_t)i * H_, lnb + (size_t)i * H_, ucm);
    }
    k_decoder<<<M_ / 64, 256, 0, stream>>>(hfr, out_W, out_b, (float*)d_out);
}

// Round 12
// 442.098 us; speedup vs baseline: 1.1771x; 1.0932x over previous
//
#include <hip/hip_runtime.h>
#include <hip/hip_bf16.h>

// ---------------------------------------------------------------------------
// S4D stack, MFMA everywhere:
// encoder GEMM(+cm,+hfr) -> 4x[ mats; fused SSM (u->LDS swz, state MFMA +
//   segmented LDS scan + Toeplitz conv MFMA); GLU MFMA + LN (A staged from
//   channel-major ycm via LDS, bf16 hfr residual, writes next ucm) ] ->
// decoder (reads hfr).
// hfr: bf16 fragment-contiguous on 64-row groups: chunk tid32=(mi*4+nq)*64+l:
//   [sub(2)][nj(4)][r(4)] -> row=mi*32+sub*16+(l>>4)*4+r, col=nq*64+nj*16+(l&15)
// ---------------------------------------------------------------------------

constexpr int B_ = 4, L_ = 8192, DIN = 64, H_ = 256, N2_ = 32, NL_ = 4, DOUT = 10;
constexpr int LC = 64, CHK = L_ / LC;     // 128 chunks/batch
constexpr int GCH = B_ * CHK;             // 512 global chunks
constexpr int M_ = B_ * L_;               // 32768 positions

// ws layout in float slots
constexpr size_t OFF_H    = 0;                         // bf16 hfr [M*256] (half used)
constexpr size_t OFF_WOB  = 8388608;                   // bf16 Wo NL*512*256
constexpr size_t OFF_PW   = 8650752;                   // (legacy)
constexpr size_t OFF_PCT  = 8716288;                   // f32 Ct2 pairs
constexpr size_t OFF_PWLC = 8781824;                   // f32 w^64 pairs
constexpr size_t OFF_PZ   = 8847360;                   // f32 z=dtA pairs
constexpr size_t OFF_EWT  = 8912896;                   // f32 enc W^T
constexpr size_t OFF_UCM  = 8929280;                   // bf16 [H][M] u cm
constexpr size_t OFF_YCM  = 13123584;                  // bf16 [H][M] y cm
constexpr size_t OFF_YPM  = 17317888;                  // (unused)
constexpr size_t OFF_MT   = 21512192;                  // bf16 Ttr [H][64][64]
constexpr size_t OFF_MW   = 22036480;                  // bf16 Wtr
constexpr size_t OFF_MV   = 22560768;                  // bf16 Vtr
// end 23085056 slots = 92.3 MB

typedef short bf16x8 __attribute__((ext_vector_type(8)));
typedef short short8 __attribute__((ext_vector_type(8)));
typedef float f32x4  __attribute__((ext_vector_type(4)));

__device__ __forceinline__ float b2f(short s) {
    union { float f; unsigned u; } c;
    c.u = ((unsigned)(unsigned short)s) << 16;
    return c.f;
}

// ---------------------------------------------------------------------------
__global__ __launch_bounds__(256) void k_params(
    const float* __restrict__ log_dt, const float* __restrict__ log_A_re,
    const float* __restrict__ A_im, const float* __restrict__ C_re,
    const float* __restrict__ C_im, float* __restrict__ ws)
{
    int idx = blockIdx.x * 256 + threadIdx.x;     // over NL*H*N2
    if (idx >= NL_ * H_ * N2_) return;
    int i  = idx / (H_ * N2_);
    int hh = (idx / N2_) % H_;
    float dt  = expf(log_dt[i * H_ + hh]);
    float Are = -expf(log_A_re[idx]);
    float Aim = A_im[idx];
    float zre = dt * Are, zim = dt * Aim;
    float er  = expf(zre);
    float wre = er * cosf(zim), wim = er * sinf(zim);
    float d   = Are * Are + Aim * Aim;
    float nre = wre - 1.f, nim = wim;
    float qre = (nre * Are + nim * Aim) / d;
    float qim = (nim * Are - nre * Aim) / d;
    float cr = C_re[idx], ci = C_im[idx];
    float ctre = cr * qre - ci * qim;
    float ctim = cr * qim + ci * qre;
    float er2 = expf(zre * (float)LC);
    float wlre = er2 * cosf(zim * (float)LC);
    float wlim = er2 * sinf(zim * (float)LC);
    ((float2*)(ws + OFF_PW))[idx]   = make_float2(wre, wim);
    ((float2*)(ws + OFF_PCT))[idx]  = make_float2(2.f * ctre, 2.f * ctim);
    ((float2*)(ws + OFF_PWLC))[idx] = make_float2(wlre, wlim);
    ((float2*)(ws + OFF_PZ))[idx]   = make_float2(zre, zim);
}

// ---------------------------------------------------------------------------
// per-channel bf16 matrices: Ttr[t][j]=k[t-j], Wtr[m][j], Vtr[t][m]
__global__ __launch_bounds__(256) void k_mats(const float* __restrict__ ws,
    int layer, __hip_bfloat16* __restrict__ mt, __hip_bfloat16* __restrict__ mw,
    __hip_bfloat16* __restrict__ mv)
{
    int h = blockIdx.x, tid = threadIdx.x;
    __shared__ float zre[32], zim[32], ctr[32], cti[32], kv[64];
    if (tid < 32) {
        float2 z = ((const float2*)(ws + OFF_PZ))[(size_t)layer*H_*N2_ + h*N2_ + tid];
        float2 c = ((const float2*)(ws + OFF_PCT))[(size_t)layer*H_*N2_ + h*N2_ + tid];
        zre[tid] = z.x; zim[tid] = z.y; ctr[tid] = c.x; cti[tid] = c.y;
    }
    __syncthreads();
    if (tid < 64) {
        float d = (float)tid, acc = 0.f;
        for (int n = 0; n < 32; n++) {
            float er = expf(zre[n] * d);
            float co = cosf(zim[n] * d), si = sinf(zim[n] * d);
            acc += er * (ctr[n] * co - cti[n] * si);
        }
        kv[tid] = acc;
    }
    __syncthreads();
    {   // Ttr
        int t = tid >> 2, j0 = (tid & 3) * 16;
        alignas(16) __hip_bfloat16 row[16];
        #pragma unroll
        for (int jj = 0; jj < 16; jj++) {
            int j = j0 + jj;
            row[jj] = __float2bfloat16(j <= t ? kv[t - j] : 0.f);
        }
        *(short8*)(mt + (size_t)h*4096 + t*64 + j0)     = *(short8*)&row[0];
        *(short8*)(mt + (size_t)h*4096 + t*64 + j0 + 8) = *(short8*)&row[8];
    }
    {   // Wtr
        int n = tid >> 3, j0 = (tid & 7) * 8;
        alignas(16) __hip_bfloat16 rre[8], rim[8];
        #pragma unroll
        for (int jj = 0; jj < 8; jj++) {
            float e = (float)(63 - (j0 + jj));
            float er = expf(zre[n] * e);
            rre[jj] = __float2bfloat16(er * cosf(zim[n] * e));
            rim[jj] = __float2bfloat16(er * sinf(zim[n] * e));
        }
        *(short8*)(mw + (size_t)h*4096 + (2*n)*64 + j0)   = *(short8*)&rre[0];
        *(short8*)(mw + (size_t)h*4096 + (2*n+1)*64 + j0) = *(short8*)&rim[0];
    }
    {   // Vtr
        int t = tid >> 2, n0 = (tid & 3) * 8;
        float e = (float)(t + 1);
        alignas(16) __hip_bfloat16 row[16];
        #pragma unroll
        for (int k = 0; k < 8; k++) {
            int n = n0 + k;
            float er = expf(zre[n] * e);
            float wr = er * cosf(zim[n] * e), wi = er * sinf(zim[n] * e);
            row[2*k]   = __float2bfloat16(ctr[n]*wr - cti[n]*wi);
            row[2*k+1] = __float2bfloat16(-(ctr[n]*wi + cti[n]*wr));
        }
        *(short8*)(mv + (size_t)h*4096 + t*64 + 2*n0)     = *(short8*)&row[0];
        *(short8*)(mv + (size_t)h*4096 + t*64 + 2*n0 + 8) = *(short8*)&row[8];
    }
}

// ---------------------------------------------------------------------------
__global__ __launch_bounds__(256) void k_transpose(const float* __restrict__ src,
    float* __restrict__ dst, int R, int Cc)
{
    __shared__ float t[32][33];
    int x = blockIdx.x * 32 + threadIdx.x;
    #pragma unroll
    for (int i = 0; i < 4; i++) {
        int yy = blockIdx.y * 32 + threadIdx.y + i * 8;
        if (x < Cc && yy < R) t[threadIdx.y + i * 8][threadIdx.x] = src[(size_t)yy * Cc + x];
    }
    __syncthreads();
    int xo = blockIdx.y * 32 + threadIdx.x;
    #pragma unroll
    for (int i = 0; i < 4; i++) {
        int yo = blockIdx.x * 32 + threadIdx.y + i * 8;
        if (xo < R && yo < Cc) dst[(size_t)yo * R + xo] = t[threadIdx.x][threadIdx.y + i * 8];
    }
}

// ---------------------------------------------------------------------------
__global__ __launch_bounds__(256) void k_wcvt(const float* __restrict__ src,
    __hip_bfloat16* __restrict__ dst, int n4)
{
    int i = blockIdx.x * 256 + threadIdx.x;
    if (i >= n4) return;
    float4 v = ((const float4*)src)[i];
    union { __hip_bfloat16 b[4]; uint2 u; } o;
    o.b[0] = __float2bfloat16(v.x); o.b[1] = __float2bfloat16(v.y);
    o.b[2] = __float2bfloat16(v.z); o.b[3] = __float2bfloat16(v.w);
    ((uint2*)dst)[i] = o.u;
}

// ---------------------------------------------------------------------------
// encoder: h = x @ encWT + b; writes hfr (bf16 fragment layout) + ucm bf16 cm
__global__ __launch_bounds__(256) void k_encoder(const float* __restrict__ x,
    const float* __restrict__ encWT, const float* __restrict__ enc_b,
    __hip_bfloat16* __restrict__ hfr, __hip_bfloat16* __restrict__ ucm)
{
    __shared__ float As[DIN][36];
    __shared__ float Bs[32][268];          // B-tiles; later f32 stage [32 pos][256 ch]
    int m0e = blockIdx.x * 32;
    int tid = threadIdx.x;
    const float4* x4 = (const float4*)x;
    #pragma unroll
    for (int q = 0; q < 2; q++) {
        int f = tid * 2 + q;
        int row = f >> 4, kq = f & 15;
        float4 v = x4[(size_t)(m0e + row) * 16 + kq];
        As[kq * 4 + 0][row] = v.x; As[kq * 4 + 1][row] = v.y;
        As[kq * 4 + 2][row] = v.z; As[kq * 4 + 3][row] = v.w;
    }
    int tx = tid & 31, ty = tid >> 5;
    float acc[4][8];
    #pragma unroll
    for (int p = 0; p < 4; p++)
        #pragma unroll
        for (int j = 0; j < 8; j++) acc[p][j] = 0.f;
    const float4* w4 = (const float4*)encWT;
    for (int ks = 0; ks < 2; ks++) {
        __syncthreads();
        #pragma unroll
        for (int it = 0; it < 8; it++) {
            int q = it * 256 + tid;
            int row = q >> 6, c4 = q & 63;
            *(float4*)&Bs[row][c4 * 4] = w4[ks * 2048 + q];
        }
        __syncthreads();
        #pragma unroll 8
        for (int kk = 0; kk < 32; kk++) {
            int k = ks * 32 + kk;
            float4 a  = *(const float4*)&As[k][ty * 4];
            float4 b0 = *(const float4*)&Bs[kk][tx * 4];
            float4 b1 = *(const float4*)&Bs[kk][128 + tx * 4];
            float av[4] = {a.x, a.y, a.z, a.w};
            float bv[8] = {b0.x, b0.y, b0.z, b0.w, b1.x, b1.y, b1.z, b1.w};
            #pragma unroll
            for (int p = 0; p < 4; p++)
                #pragma unroll
                for (int j = 0; j < 8; j++)
                    acc[p][j] = fmaf(av[p], bv[j], acc[p][j]);
        }
    }
    float4 eb0 = *(const float4*)&enc_b[tx * 4];
    float4 eb1 = *(const float4*)&enc_b[128 + tx * 4];
    float ebv[8] = {eb0.x, eb0.y, eb0.z, eb0.w, eb1.x, eb1.y, eb1.z, eb1.w};
    __syncthreads();                       // Bs dead -> f32 stage st2[pl][ch]
    #pragma unroll
    for (int p = 0; p < 4; p++) {
        int pl = ty * 4 + p;
        #pragma unroll
        for (int j = 0; j < 4; j++) Bs[pl][tx * 4 + j]       = acc[p][j] + ebv[j];
        #pragma unroll
        for (int j = 0; j < 4; j++) Bs[pl][128 + tx * 4 + j] = acc[p][j + 4] + ebv[j + 4];
    }
    __syncthreads();
    // hfr write: fragment threads, 32 contiguous bf16 each
    {
        size_t m0 = (size_t)(m0e & ~63);
        int mi = (m0e >> 5) & 1;
        int nq = tid >> 6, l = tid & 63, l4 = l >> 4, l15 = l & 15;
        int tid32 = (mi * 4 + nq) * 64 + l;
        __hip_bfloat16* dst = hfr + m0 * 256 + (size_t)tid32 * 32;
        alignas(16) __hip_bfloat16 tmp[32];
        #pragma unroll
        for (int sub = 0; sub < 2; sub++)
            #pragma unroll
            for (int nj = 0; nj < 4; nj++) {
                int pl = sub * 16 + l4 * 4;
                int cn = nq * 64 + nj * 16 + l15;
                #pragma unroll
                for (int r = 0; r < 4; r++)
                    tmp[sub * 16 + nj * 4 + r] = __float2bfloat16(Bs[pl + r][cn]);
            }
        #pragma unroll
        for (int q = 0; q < 4; q++)
            *(short8*)(dst + q * 8) = *(short8*)&tmp[q * 8];
    }
    // ucm write: thread = channel
    {
        alignas(16) __hip_bfloat16 row[32];
        #pragma unroll
        for (int pl = 0; pl < 32; pl++) row[pl] = __float2bfloat16(Bs[pl][tid]);
        #pragma unroll
        for (int q = 0; q < 4; q++)
            *(short8*)(ucm + (size_t)tid * M_ + m0e + q * 8) = *(short8*)&row[q * 8];
    }
}

// ---------------------------------------------------------------------------
// FUSED SSM: block = (channel, batch). u staged in XOR-swizzled LDS.
// Phase1: chunk-state MFMA -> swz LDS. Phase2: 8-way segmented scan. Phase3:
// conv MFMA + carry + GELU. swizzle: elem e of chunk c at c*64 + (e^((c&7)<<3))
__global__ __launch_bounds__(256) void k_ssm(const __hip_bfloat16* __restrict__ ucm,
    const __hip_bfloat16* __restrict__ mt, const __hip_bfloat16* __restrict__ mw,
    const __hip_bfloat16* __restrict__ mv, const float* __restrict__ ws, int layer,
    const float* __restrict__ Dp, __hip_bfloat16* __restrict__ ycm)
{
    __shared__ __hip_bfloat16 ulds[L_];       // 16 KB swizzled u
    __shared__ __hip_bfloat16 st[CHK * 64];   // 16 KB swizzled states
    __shared__ float segT[8][32][2];          // 2 KB segment totals
    int h = blockIdx.x >> 2, b = blockIdx.x & 3;
    int tid = threadIdx.x, w = tid >> 6, l = tid & 63, l15 = l & 15, l4 = l >> 4;
    const __hip_bfloat16* ub = ucm + (size_t)h * M_ + (size_t)b * L_;
    #pragma unroll
    for (int it = 0; it < 4; it++) {
        int e0 = it * 2048 + tid * 8;
        short8 v = *(const short8*)(ub + e0);
        int c = e0 >> 6, e = e0 & 63;
        *(short8*)&ulds[c * 64 + (e ^ ((c & 7) << 3))] = v;
    }
    __syncthreads();
    {
        const __hip_bfloat16* bbase = mw + (size_t)h * 4096 + l15 * 64 + l4 * 8;
        #pragma unroll
        for (int half = 0; half < 2; half++) {
            int g0 = (w + half * 4) * 16;
            int ca = g0 + l15;
            f32x4 acc[4];
            #pragma unroll
            for (int nj = 0; nj < 4; nj++) acc[nj] = (f32x4)0.f;
            #pragma unroll
            for (int ks = 0; ks < 2; ks++) {
                int e = l4 * 8 + ks * 32;
                bf16x8 a = *(const bf16x8*)&ulds[ca * 64 + (e ^ ((ca & 7) << 3))];
                #pragma unroll
                for (int nj = 0; nj < 4; nj++) {
                    bf16x8 bb = *(const bf16x8*)(bbase + nj * 16 * 64 + ks * 32);
                    acc[nj] = __builtin_amdgcn_mfma_f32_16x16x32_bf16(a, bb, acc[nj], 0, 0, 0);
                }
            }
            #pragma unroll
            for (int nj = 0; nj < 4; nj++)
                #pragma unroll
                for (int r = 0; r < 4; r++) {
                    int c = g0 + l4 * 4 + r, e = nj * 16 + l15;
                    st[c * 64 + (e ^ ((c & 7) << 3))] = __float2bfloat16(acc[nj][r]);
                }
        }
    }
    __syncthreads();
    {
        int s = tid >> 5, n = tid & 31;
        float2 wl = ((const float2*)(ws + OFF_PWLC))[(size_t)layer * H_ * N2_ + h * 32 + n];
        float tr = 0.f, ti = 0.f;
        for (int j = 0; j < 16; j++) {
            int c = s * 16 + j;
            __hip_bfloat162* p = (__hip_bfloat162*)&st[c * 64 + ((2 * n) ^ ((c & 7) << 3))];
            float2 v = __bfloat1622float2(*p);
            float nr = fmaf(wl.x, tr, v.x); nr = fmaf(-wl.y, ti, nr);
            float ni = fmaf(wl.x, ti, v.y); ni = fmaf(wl.y, tr, ni);
            tr = nr; ti = ni;
        }
        segT[s][n][0] = tr; segT[s][n][1] = ti;
        __syncthreads();
        float wr = wl.x, wi = wl.y;
        #pragma unroll
        for (int q = 0; q < 4; q++) {
            float nr = wr * wr - wi * wi, ni = 2.f * wr * wi;
            wr = nr; wi = ni;
        }
        float ar = 0.f, ai = 0.f;
        for (int t = 0; t < s; t++) {
            float Tx = segT[t][n][0], Ty = segT[t][n][1];
            float nr = fmaf(wr, ar, Tx); nr = fmaf(-wi, ai, nr);
            float ni = fmaf(wr, ai, Ty); ni = fmaf(wi, ar, ni);
            ar = nr; ai = ni;
        }
        for (int j = 0; j < 16; j++) {
            int c = s * 16 + j;
            __hip_bfloat162* p = (__hip_bfloat162*)&st[c * 64 + ((2 * n) ^ ((c & 7) << 3))];
            float2 v = __bfloat1622float2(*p);
            *p = __float22bfloat162_rn(make_float2(ar, ai));
            float nr = fmaf(wl.x, ar, v.x); nr = fmaf(-wl.y, ai, nr);
            float ni = fmaf(wl.x, ai, v.y); ni = fmaf(wl.y, ar, ni);
            ar = nr; ai = ni;
        }
    }
    __syncthreads();
    {
        const __hip_bfloat16* bt = mt + (size_t)h * 4096 + l15 * 64 + l4 * 8;
        const __hip_bfloat16* bv = mv + (size_t)h * 4096 + l15 * 64 + l4 * 8;
        float Dh = Dp[layer * H_ + h];
        __hip_bfloat16* yb = ycm + (size_t)h * M_ + (size_t)b * L_;
        #pragma unroll
        for (int half = 0; half < 2; half++) {
            int g0 = (w + half * 4) * 16;
            int ca = g0 + l15;
            f32x4 acc[4];
            #pragma unroll
            for (int nj = 0; nj < 4; nj++) acc[nj] = (f32x4)0.f;
            #pragma unroll
            for (int ks = 0; ks < 2; ks++) {
                int e = l4 * 8 + ks * 32;
                bf16x8 a = *(const bf16x8*)&ulds[ca * 64 + (e ^ ((ca & 7) << 3))];
                #pragma unroll
                for (int nj = 0; nj < 4; nj++) {
                    bf16x8 bb = *(const bf16x8*)(bt + nj * 16 * 64 + ks * 32);
                    acc[nj] = __builtin_amdgcn_mfma_f32_16x16x32_bf16(a, bb, acc[nj], 0, 0, 0);
                }
            }
            #pragma unroll
            for (int ks = 0; ks < 2; ks++) {
                int e = l4 * 8 + ks * 32;
                bf16x8 a = *(const bf16x8*)&st[ca * 64 + (e ^ ((ca & 7) << 3))];
                #pragma unroll
                for (int nj = 0; nj < 4; nj++) {
                    bf16x8 bb = *(const bf16x8*)(bv + nj * 16 * 64 + ks * 32);
                    acc[nj] = __builtin_amdgcn_mfma_f32_16x16x32_bf16(a, bb, acc[nj], 0, 0, 0);
                }
            }
            #pragma unroll
            for (int nj = 0; nj < 4; nj++)
                #pragma unroll
                for (int r = 0; r < 4; r++) {
                    int g = g0 + l4 * 4 + r;
                    int e = nj * 16 + l15;
                    float uv = __bfloat162float(ulds[g * 64 + (e ^ ((g & 7) << 3))]);
                    float v = fmaf(Dh, uv, acc[nj][r]);
                    float gg = 0.7978845608028654f * fmaf(0.044715f * v, v * v, v);
                    float yv = v / (1.f + __expf(-2.f * gg));
                    yb[(size_t)g * 64 + nj * 16 + l15] = __float2bfloat16(yv);
                }
        }
    }
}

// ---------------------------------------------------------------------------
// fused MFMA GLU+LN v9: BM=32, grid 1024. A staged from channel-major ycm
// (thread=channel load, LDS [ch][36]); bf16 hfr residual prefetched early;
// epilogue writes bf16 hfr + next-layer ucm (lt aliases the A-LDS).
__global__ __launch_bounds__(256) void k_glu_mfma(
    const __hip_bfloat16* __restrict__ ycm,  // [H][M] bf16 cm
    __hip_bfloat16* __restrict__ hfr,        // bf16 fragment-layout
    const __hip_bfloat16* __restrict__ wob,  // [512,256] bf16
    const float* __restrict__ bo, const float* __restrict__ lnw,
    const float* __restrict__ lnb, __hip_bfloat16* __restrict__ un)
{
    __shared__ __hip_bfloat16 ylds[256 * 36];  // A-tile [ch][32pos+pad] / lt reuse
    __shared__ float red[4][32][2];
    int tid = threadIdx.x;
    int w = tid >> 6, l = tid & 63, l15 = l & 15, l4 = l >> 4;
    int m0 = blockIdx.x * 32;
    int mi = (m0 >> 5) & 1;
    int nv = w * 64;

    // ---- A stage: thread = channel, 32 positions (coalesced per ycm row)
    {
        const __hip_bfloat16* src = ycm + (size_t)tid * M_ + m0;
        short8 sv[4];
        #pragma unroll
        for (int q = 0; q < 4; q++) sv[q] = *(const short8*)(src + q * 8);
        #pragma unroll
        for (int q = 0; q < 4; q++)
            *(short8*)&ylds[tid * 36 + q * 8] = sv[q];
    }
    // residual prefetch EARLY (64 B/thread; latency hides under K-loop)
    __hip_bfloat16* hbase = hfr + (size_t)(m0 & ~63) * 256
                            + ((size_t)((mi * 4 + w) * 64 + l)) * 32;
    bf16x8 hraw[4];
    #pragma unroll
    for (int q = 0; q < 4; q++) hraw[q] = *(const bf16x8*)(hbase + q * 8);
    __syncthreads();

    f32x4 accv[2][4], accg[2][4];
    #pragma unroll
    for (int sub = 0; sub < 2; sub++)
        #pragma unroll
        for (int nj = 0; nj < 4; nj++) { accv[sub][nj] = (f32x4)0.f; accg[sub][nj] = (f32x4)0.f; }

    #pragma unroll 2
    for (int ks = 0; ks < 8; ks++) {
        int k0 = ks * 32 + l4 * 8;
        // A-fragments from LDS: 8 channels (k0..k0+7) at pos l15 / 16+l15
        alignas(16) short fa0[8], fa1[8];
        #pragma unroll
        for (int j = 0; j < 8; j++) {
            fa0[j] = *(short*)&ylds[(k0 + j) * 36 + l15];
            fa1[j] = *(short*)&ylds[(k0 + j) * 36 + 16 + l15];
        }
        bf16x8 a0 = *(bf16x8*)fa0;
        bf16x8 a1 = *(bf16x8*)fa1;
        #pragma unroll
        for (int nj = 0; nj < 4; nj++) {
            bf16x8 bv = *(const bf16x8*)(wob + (size_t)(nv + nj * 16 + l15) * H_ + k0);
            bf16x8 bg = *(const bf16x8*)(wob + (size_t)(256 + nv + nj * 16 + l15) * H_ + k0);
            accv[0][nj] = __builtin_amdgcn_mfma_f32_16x16x32_bf16(a0, bv, accv[0][nj], 0, 0, 0);
            accg[0][nj] = __builtin_amdgcn_mfma_f32_16x16x32_bf16(a0, bg, accg[0][nj], 0, 0, 0);
            accv[1][nj] = __builtin_amdgcn_mfma_f32_16x16x32_bf16(a1, bv, accv[1][nj], 0, 0, 0);
            accg[1][nj] = __builtin_amdgcn_mfma_f32_16x16x32_bf16(a1, bg, accg[1][nj], 0, 0, 0);
        }
    }

    float bov[4], bog[4], lw[4], lb[4];
    #pragma unroll
    for (int nj = 0; nj < 4; nj++) {
        int cn = nv + nj * 16 + l15;
        bov[nj] = bo[cn]; bog[nj] = bo[256 + cn];
        lw[nj] = lnw[cn]; lb[nj] = lnb[cn];
    }
    #pragma unroll
    for (int sub = 0; sub < 2; sub++) {
        #pragma unroll
        for (int r = 0; r < 4; r++) {
            int lr = sub * 16 + l4 * 4 + r;
            float s = 0.f, ss = 0.f;
            #pragma unroll
            for (int nj = 0; nj < 4; nj++) {
                int idx = sub * 16 + nj * 4 + r;
                float uv = accv[sub][nj][r] + bov[nj];
                float ug = accg[sub][nj][r] + bog[nj];
                float z = uv / (1.f + __expf(-ug));
                float v = z + b2f(hraw[idx >> 3][idx & 7]);
                accv[sub][nj][r] = v;
                s += v; ss += v * v;
            }
            #pragma unroll
            for (int off = 1; off < 16; off <<= 1) {
                s  += __shfl_xor(s, off);
                ss += __shfl_xor(ss, off);
            }
            if (l15 == 0) { red[w][lr][0] = s; red[w][lr][1] = ss; }
        }
    }
    __syncthreads();                 // ylds reads done -> reuse as lt
    alignas(16) __hip_bfloat16 tmp[32];
    #pragma unroll
    for (int sub = 0; sub < 2; sub++) {
        #pragma unroll
        for (int r = 0; r < 4; r++) {
            int lr = sub * 16 + l4 * 4 + r;
            float s  = red[0][lr][0] + red[1][lr][0] + red[2][lr][0] + red[3][lr][0];
            float ss = red[0][lr][1] + red[1][lr][1] + red[2][lr][1] + red[3][lr][1];
            float mu = s * (1.f / 256.f);
            float var = ss * (1.f / 256.f) - mu * mu;
            float rstd = rsqrtf(var + 1e-5f);
            #pragma unroll
            for (int nj = 0; nj < 4; nj++) {
                int cn = nv + nj * 16 + l15;
                int idx = sub * 16 + nj * 4 + r;
                float val = (accv[sub][nj][r] - mu) * rstd * lw[nj] + lb[nj];
                __hip_bfloat16 bval = __float2bfloat16(val);
                tmp[idx] = bval;
                ylds[cn * 36 + lr] = bval;
            }
        }
    }
    // hfr write: 64 B/thread contiguous
    #pragma unroll
    for (int q = 0; q < 4; q++)
        *(short8*)(hbase + q * 8) = *(short8*)&tmp[q * 8];
    __syncthreads();
    {   // ucm write: thread = channel, 32 positions
        #pragma unroll
        for (int q = 0; q < 4; q++)
            *(short8*)(un + (size_t)tid * M_ + m0 + q * 8)
                = *(short8*)&ylds[tid * 36 + q * 8];
    }
}

// ---------------------------------------------------------------------------
// decoder: reads bf16 hfr (fragment layout) via LDS unscramble; 64-pos tiles
__global__ __launch_bounds__(256) void k_decoder(const __hip_bfloat16* __restrict__ hfr,
    const float* __restrict__ out_W, const float* __restrict__ out_b,
    float* __restrict__ out)
{
    __shared__ float hs[64][260];
    __shared__ float wl[10][260];
    int m0 = blockIdx.x * 64;
    int tid = threadIdx.x;
    #pragma unroll
    for (int half = 0; half < 2; half++) {
        int cid = half * 256 + tid;          // tid32 chunk id
        int cw = cid >> 6, cl = cid & 63;
        int cmi = cw >> 2, cnq = cw & 3, cl4 = cl >> 4, cl15 = cl & 15;
        const bf16x8* src = (const bf16x8*)(hfr + (size_t)m0 * 256 + (size_t)cid * 32);
        bf16x8 raw[4];
        #pragma unroll
        for (int q = 0; q < 4; q++) raw[q] = src[q];
        #pragma unroll
        for (int sub = 0; sub < 2; sub++)
            #pragma unroll
            for (int nj = 0; nj < 4; nj++) {
                int row = cmi * 32 + sub * 16 + cl4 * 4;
                int col = cnq * 64 + nj * 16 + cl15;
                #pragma unroll
                for (int r = 0; r < 4; r++) {
                    int idx = sub * 16 + nj * 4 + r;
                    hs[row + r][col] = b2f(raw[idx >> 3][idx & 7]);
                }
            }
    }
    for (int q = tid; q < 640; q += 256) {
        int r = q / 64, k4 = q % 64;
        *(float4*)&wl[r][k4 * 4] = ((const float4*)out_W)[q];
    }
    __syncthreads();
    int slot = tid & 15;
    if (slot < DOUT) {
        #pragma unroll
        for (int pass = 0; pass < 4; pass++) {
            int pl = pass * 16 + (tid >> 4);
            float a0 = 0.f, a1 = 0.f, a2 = 0.f, a3 = 0.f;
            #pragma unroll 8
            for (int k = 0; k < 256; k += 4) {
                a0 = fmaf(hs[pl][k + 0], wl[slot][k + 0], a0);
                a1 = fmaf(hs[pl][k + 1], wl[slot][k + 1], a1);
                a2 = fmaf(hs[pl][k + 2], wl[slot][k + 2], a2);
                a3 = fmaf(hs[pl][k + 3], wl[slot][k + 3], a3);
            }
            out[(size_t)(m0 + pl) * DOUT + slot] = (a0 + a1) + (a2 + a3) + out_b[slot];
        }
    }
}

// ---------------------------------------------------------------------------
extern "C" void kernel_launch(void* const* d_in, const int* in_sizes, int n_in,
                              void* d_out, int out_size, void* d_ws, size_t ws_size,
                              hipStream_t stream)
{
    (void)in_sizes; (void)n_in; (void)out_size; (void)ws_size;
    const float* x        = (const float*)d_in[0];
    const float* enc_W    = (const float*)d_in[1];
    const float* enc_b    = (const float*)d_in[2];
    const float* log_dt   = (const float*)d_in[3];
    const float* log_A_re = (const float*)d_in[4];
    const float* A_im     = (const float*)d_in[5];
    const float* C_re     = (const float*)d_in[6];
    const float* C_im     = (const float*)d_in[7];
    const float* Dp       = (const float*)d_in[8];
    const float* Wo       = (const float*)d_in[9];
    const float* bo       = (const float*)d_in[10];
    const float* lnw      = (const float*)d_in[11];
    const float* lnb      = (const float*)d_in[12];
    const float* out_W    = (const float*)d_in[13];
    const float* out_b    = (const float*)d_in[14];
    float* ws = (float*)d_ws;
    __hip_bfloat16* hfr = (__hip_bfloat16*)(ws + OFF_H);
    __hip_bfloat16* ucm = (__hip_bfloat16*)(ws + OFF_UCM);
    __hip_bfloat16* ycm = (__hip_bfloat16*)(ws + OFF_YCM);
    __hip_bfloat16* mt = (__hip_bfloat16*)(ws + OFF_MT);
    __hip_bfloat16* mw = (__hip_bfloat16*)(ws + OFF_MW);
    __hip_bfloat16* mv = (__hip_bfloat16*)(ws + OFF_MV);
    __hip_bfloat16* wob = (__hip_bfloat16*)(ws + OFF_WOB);

    k_params<<<NL_ * H_ * N2_ / 256, 256, 0, stream>>>(log_dt, log_A_re, A_im, C_re, C_im, ws);
    dim3 tb(32, 8);
    k_transpose<<<dim3(DIN / 32, H_ / 32), tb, 0, stream>>>(enc_W, ws + OFF_EWT, H_, DIN);
    k_wcvt<<<(NL_ * 2 * H_ * H_ / 4 + 255) / 256, 256, 0, stream>>>(Wo, wob, NL_ * 2 * H_ * H_ / 4);
    k_encoder<<<M_ / 32, 256, 0, stream>>>(x, ws + OFF_EWT, enc_b, hfr, ucm);
    for (int i = 0; i < NL_; i++) {
        k_mats<<<H_, 256, 0, stream>>>(ws, i, mt, mw, mv);
        k_ssm<<<H_ * B_, 256, 0, stream>>>(ucm, mt, mw, mv, ws, i, Dp, ycm);
        k_glu_mfma<<<M_ / 32, 256, 0, stream>>>(ycm, hfr,
            wob + (size_t)i * 2 * H_ * H_, bo + (size_t)i * 2 * H_,
            lnw + (size_t)i * H_, lnb + (size_t)i * H_, ucm);
    }
    k_decoder<<<M_ / 64, 256, 0, stream>>>(hfr, out_W, out_b, (float*)d_out);
}

// Round 13
// 441.823 us; speedup vs baseline: 1.1778x; 1.0006x over previous
//
#include <hip/hip_runtime.h>
#include <hip/hip_bf16.h>

// ---------------------------------------------------------------------------
// S4D stack, MFMA everywhere:
// encoder GEMM(+cm,+hfr) -> 4x[ mats; fused SSM (u->LDS swz, state MFMA +
//   segmented LDS scan + Toeplitz conv MFMA); GLU MFMA + LN (A staged from
//   channel-major ycm via pair-interleaved LDS, bf16 hfr residual, writes
//   next ucm) ] -> decoder (reads hfr).
// hfr: bf16 fragment-contiguous on 64-row groups: chunk tid32=(mi*4+nq)*64+l:
//   [sub(2)][nj(4)][r(4)] -> row=mi*32+sub*16+(l>>4)*4+r, col=nq*64+nj*16+(l&15)
// glu A-LDS: dword[pos][130]: dword p of row pos = short2(ch 2p, ch 2p+1)
// ---------------------------------------------------------------------------

constexpr int B_ = 4, L_ = 8192, DIN = 64, H_ = 256, N2_ = 32, NL_ = 4, DOUT = 10;
constexpr int LC = 64, CHK = L_ / LC;     // 128 chunks/batch
constexpr int GCH = B_ * CHK;             // 512 global chunks
constexpr int M_ = B_ * L_;               // 32768 positions

// ws layout in float slots
constexpr size_t OFF_H    = 0;                         // bf16 hfr [M*256] (half used)
constexpr size_t OFF_WOB  = 8388608;                   // bf16 Wo NL*512*256
constexpr size_t OFF_PW   = 8650752;                   // (legacy)
constexpr size_t OFF_PCT  = 8716288;                   // f32 Ct2 pairs
constexpr size_t OFF_PWLC = 8781824;                   // f32 w^64 pairs
constexpr size_t OFF_PZ   = 8847360;                   // f32 z=dtA pairs
constexpr size_t OFF_EWT  = 8912896;                   // f32 enc W^T
constexpr size_t OFF_UCM  = 8929280;                   // bf16 [H][M] u cm
constexpr size_t OFF_YCM  = 13123584;                  // bf16 [H][M] y cm
constexpr size_t OFF_MT   = 21512192;                  // bf16 Ttr [H][64][64]
constexpr size_t OFF_MW   = 22036480;                  // bf16 Wtr
constexpr size_t OFF_MV   = 22560768;                  // bf16 Vtr
// end 23085056 slots = 92.3 MB

typedef short bf16x8 __attribute__((ext_vector_type(8)));
typedef short short8 __attribute__((ext_vector_type(8)));
typedef float f32x4  __attribute__((ext_vector_type(4)));
typedef int   int2v  __attribute__((ext_vector_type(2)));

__device__ __forceinline__ float b2f(short s) {
    union { float f; unsigned u; } c;
    c.u = ((unsigned)(unsigned short)s) << 16;
    return c.f;
}

// ---------------------------------------------------------------------------
__global__ __launch_bounds__(256) void k_params(
    const float* __restrict__ log_dt, const float* __restrict__ log_A_re,
    const float* __restrict__ A_im, const float* __restrict__ C_re,
    const float* __restrict__ C_im, float* __restrict__ ws)
{
    int idx = blockIdx.x * 256 + threadIdx.x;     // over NL*H*N2
    if (idx >= NL_ * H_ * N2_) return;
    int i  = idx / (H_ * N2_);
    int hh = (idx / N2_) % H_;
    float dt  = expf(log_dt[i * H_ + hh]);
    float Are = -expf(log_A_re[idx]);
    float Aim = A_im[idx];
    float zre = dt * Are, zim = dt * Aim;
    float er  = expf(zre);
    float wre = er * cosf(zim), wim = er * sinf(zim);
    float d   = Are * Are + Aim * Aim;
    float nre = wre - 1.f, nim = wim;
    float qre = (nre * Are + nim * Aim) / d;
    float qim = (nim * Are - nre * Aim) / d;
    float cr = C_re[idx], ci = C_im[idx];
    float ctre = cr * qre - ci * qim;
    float ctim = cr * qim + ci * qre;
    float er2 = expf(zre * (float)LC);
    float wlre = er2 * cosf(zim * (float)LC);
    float wlim = er2 * sinf(zim * (float)LC);
    ((float2*)(ws + OFF_PW))[idx]   = make_float2(wre, wim);
    ((float2*)(ws + OFF_PCT))[idx]  = make_float2(2.f * ctre, 2.f * ctim);
    ((float2*)(ws + OFF_PWLC))[idx] = make_float2(wlre, wlim);
    ((float2*)(ws + OFF_PZ))[idx]   = make_float2(zre, zim);
}

// ---------------------------------------------------------------------------
// per-channel bf16 matrices: Ttr[t][j]=k[t-j], Wtr[m][j], Vtr[t][m]
__global__ __launch_bounds__(256) void k_mats(const float* __restrict__ ws,
    int layer, __hip_bfloat16* __restrict__ mt, __hip_bfloat16* __restrict__ mw,
    __hip_bfloat16* __restrict__ mv)
{
    int h = blockIdx.x, tid = threadIdx.x;
    __shared__ float zre[32], zim[32], ctr[32], cti[32], kv[64];
    if (tid < 32) {
        float2 z = ((const float2*)(ws + OFF_PZ))[(size_t)layer*H_*N2_ + h*N2_ + tid];
        float2 c = ((const float2*)(ws + OFF_PCT))[(size_t)layer*H_*N2_ + h*N2_ + tid];
        zre[tid] = z.x; zim[tid] = z.y; ctr[tid] = c.x; cti[tid] = c.y;
    }
    __syncthreads();
    if (tid < 64) {
        float d = (float)tid, acc = 0.f;
        for (int n = 0; n < 32; n++) {
            float er = expf(zre[n] * d);
            float co = cosf(zim[n] * d), si = sinf(zim[n] * d);
            acc += er * (ctr[n] * co - cti[n] * si);
        }
        kv[tid] = acc;
    }
    __syncthreads();
    {   // Ttr
        int t = tid >> 2, j0 = (tid & 3) * 16;
        alignas(16) __hip_bfloat16 row[16];
        #pragma unroll
        for (int jj = 0; jj < 16; jj++) {
            int j = j0 + jj;
            row[jj] = __float2bfloat16(j <= t ? kv[t - j] : 0.f);
        }
        *(short8*)(mt + (size_t)h*4096 + t*64 + j0)     = *(short8*)&row[0];
        *(short8*)(mt + (size_t)h*4096 + t*64 + j0 + 8) = *(short8*)&row[8];
    }
    {   // Wtr
        int n = tid >> 3, j0 = (tid & 7) * 8;
        alignas(16) __hip_bfloat16 rre[8], rim[8];
        #pragma unroll
        for (int jj = 0; jj < 8; jj++) {
            float e = (float)(63 - (j0 + jj));
            float er = expf(zre[n] * e);
            rre[jj] = __float2bfloat16(er * cosf(zim[n] * e));
            rim[jj] = __float2bfloat16(er * sinf(zim[n] * e));
        }
        *(short8*)(mw + (size_t)h*4096 + (2*n)*64 + j0)   = *(short8*)&rre[0];
        *(short8*)(mw + (size_t)h*4096 + (2*n+1)*64 + j0) = *(short8*)&rim[0];
    }
    {   // Vtr
        int t = tid >> 2, n0 = (tid & 3) * 8;
        float e = (float)(t + 1);
        alignas(16) __hip_bfloat16 row[16];
        #pragma unroll
        for (int k = 0; k < 8; k++) {
            int n = n0 + k;
            float er = expf(zre[n] * e);
            float wr = er * cosf(zim[n] * e), wi = er * sinf(zim[n] * e);
            row[2*k]   = __float2bfloat16(ctr[n]*wr - cti[n]*wi);
            row[2*k+1] = __float2bfloat16(-(ctr[n]*wi + cti[n]*wr));
        }
        *(short8*)(mv + (size_t)h*4096 + t*64 + 2*n0)     = *(short8*)&row[0];
        *(short8*)(mv + (size_t)h*4096 + t*64 + 2*n0 + 8) = *(short8*)&row[8];
    }
}

// ---------------------------------------------------------------------------
__global__ __launch_bounds__(256) void k_transpose(const float* __restrict__ src,
    float* __restrict__ dst, int R, int Cc)
{
    __shared__ float t[32][33];
    int x = blockIdx.x * 32 + threadIdx.x;
    #pragma unroll
    for (int i = 0; i < 4; i++) {
        int yy = blockIdx.y * 32 + threadIdx.y + i * 8;
        if (x < Cc && yy < R) t[threadIdx.y + i * 8][threadIdx.x] = src[(size_t)yy * Cc + x];
    }
    __syncthreads();
    int xo = blockIdx.y * 32 + threadIdx.x;
    #pragma unroll
    for (int i = 0; i < 4; i++) {
        int yo = blockIdx.x * 32 + threadIdx.y + i * 8;
        if (xo < R && yo < Cc) dst[(size_t)yo * R + xo] = t[threadIdx.x][threadIdx.y + i * 8];
    }
}

// ---------------------------------------------------------------------------
__global__ __launch_bounds__(256) void k_wcvt(const float* __restrict__ src,
    __hip_bfloat16* __restrict__ dst, int n4)
{
    int i = blockIdx.x * 256 + threadIdx.x;
    if (i >= n4) return;
    float4 v = ((const float4*)src)[i];
    union { __hip_bfloat16 b[4]; uint2 u; } o;
    o.b[0] = __float2bfloat16(v.x); o.b[1] = __float2bfloat16(v.y);
    o.b[2] = __float2bfloat16(v.z); o.b[3] = __float2bfloat16(v.w);
    ((uint2*)dst)[i] = o.u;
}

// ---------------------------------------------------------------------------
// encoder: h = x @ encWT + b; writes hfr (bf16 fragment layout) + ucm bf16 cm
__global__ __launch_bounds__(256) void k_encoder(const float* __restrict__ x,
    const float* __restrict__ encWT, const float* __restrict__ enc_b,
    __hip_bfloat16* __restrict__ hfr, __hip_bfloat16* __restrict__ ucm)
{
    __shared__ float As[DIN][36];
    __shared__ float Bs[32][268];          // B-tiles; later f32 stage [32 pos][256 ch]
    int m0e = blockIdx.x * 32;
    int tid = threadIdx.x;
    const float4* x4 = (const float4*)x;
    #pragma unroll
    for (int q = 0; q < 2; q++) {
        int f = tid * 2 + q;
        int row = f >> 4, kq = f & 15;
        float4 v = x4[(size_t)(m0e + row) * 16 + kq];
        As[kq * 4 + 0][row] = v.x; As[kq * 4 + 1][row] = v.y;
        As[kq * 4 + 2][row] = v.z; As[kq * 4 + 3][row] = v.w;
    }
    int tx = tid & 31, ty = tid >> 5;
    float acc[4][8];
    #pragma unroll
    for (int p = 0; p < 4; p++)
        #pragma unroll
        for (int j = 0; j < 8; j++) acc[p][j] = 0.f;
    const float4* w4 = (const float4*)encWT;
    for (int ks = 0; ks < 2; ks++) {
        __syncthreads();
        #pragma unroll
        for (int it = 0; it < 8; it++) {
            int q = it * 256 + tid;
            int row = q >> 6, c4 = q & 63;
            *(float4*)&Bs[row][c4 * 4] = w4[ks * 2048 + q];
        }
        __syncthreads();
        #pragma unroll 8
        for (int kk = 0; kk < 32; kk++) {
            int k = ks * 32 + kk;
            float4 a  = *(const float4*)&As[k][ty * 4];
            float4 b0 = *(const float4*)&Bs[kk][tx * 4];
            float4 b1 = *(const float4*)&Bs[kk][128 + tx * 4];
            float av[4] = {a.x, a.y, a.z, a.w};
            float bv[8] = {b0.x, b0.y, b0.z, b0.w, b1.x, b1.y, b1.z, b1.w};
            #pragma unroll
            for (int p = 0; p < 4; p++)
                #pragma unroll
                for (int j = 0; j < 8; j++)
                    acc[p][j] = fmaf(av[p], bv[j], acc[p][j]);
        }
    }
    float4 eb0 = *(const float4*)&enc_b[tx * 4];
    float4 eb1 = *(const float4*)&enc_b[128 + tx * 4];
    float ebv[8] = {eb0.x, eb0.y, eb0.z, eb0.w, eb1.x, eb1.y, eb1.z, eb1.w};
    __syncthreads();                       // Bs dead -> f32 stage st2[pl][ch]
    #pragma unroll
    for (int p = 0; p < 4; p++) {
        int pl = ty * 4 + p;
        #pragma unroll
        for (int j = 0; j < 4; j++) Bs[pl][tx * 4 + j]       = acc[p][j] + ebv[j];
        #pragma unroll
        for (int j = 0; j < 4; j++) Bs[pl][128 + tx * 4 + j] = acc[p][j + 4] + ebv[j + 4];
    }
    __syncthreads();
    // hfr write: fragment threads, 32 contiguous bf16 each
    {
        size_t m0 = (size_t)(m0e & ~63);
        int mi = (m0e >> 5) & 1;
        int nq = tid >> 6, l = tid & 63, l4 = l >> 4, l15 = l & 15;
        int tid32 = (mi * 4 + nq) * 64 + l;
        __hip_bfloat16* dst = hfr + m0 * 256 + (size_t)tid32 * 32;
        alignas(16) __hip_bfloat16 tmp[32];
        #pragma unroll
        for (int sub = 0; sub < 2; sub++)
            #pragma unroll
            for (int nj = 0; nj < 4; nj++) {
                int pl = sub * 16 + l4 * 4;
                int cn = nq * 64 + nj * 16 + l15;
                #pragma unroll
                for (int r = 0; r < 4; r++)
                    tmp[sub * 16 + nj * 4 + r] = __float2bfloat16(Bs[pl + r][cn]);
            }
        #pragma unroll
        for (int q = 0; q < 4; q++)
            *(short8*)(dst + q * 8) = *(short8*)&tmp[q * 8];
    }
    // ucm write: thread = channel
    {
        alignas(16) __hip_bfloat16 row[32];
        #pragma unroll
        for (int pl = 0; pl < 32; pl++) row[pl] = __float2bfloat16(Bs[pl][tid]);
        #pragma unroll
        for (int q = 0; q < 4; q++)
            *(short8*)(ucm + (size_t)tid * M_ + m0e + q * 8) = *(short8*)&row[q * 8];
    }
}

// ---------------------------------------------------------------------------
// FUSED SSM: block = (channel, batch). u staged in XOR-swizzled LDS.
// Phase1: chunk-state MFMA -> swz LDS. Phase2: 8-way segmented scan. Phase3:
// conv MFMA + carry + GELU. swizzle: elem e of chunk c at c*64 + (e^((c&7)<<3))
__global__ __launch_bounds__(256) void k_ssm(const __hip_bfloat16* __restrict__ ucm,
    const __hip_bfloat16* __restrict__ mt, const __hip_bfloat16* __restrict__ mw,
    const __hip_bfloat16* __restrict__ mv, const float* __restrict__ ws, int layer,
    const float* __restrict__ Dp, __hip_bfloat16* __restrict__ ycm)
{
    __shared__ __hip_bfloat16 ulds[L_];       // 16 KB swizzled u
    __shared__ __hip_bfloat16 st[CHK * 64];   // 16 KB swizzled states
    __shared__ float segT[8][32][2];          // 2 KB segment totals
    int h = blockIdx.x >> 2, b = blockIdx.x & 3;
    int tid = threadIdx.x, w = tid >> 6, l = tid & 63, l15 = l & 15, l4 = l >> 4;
    const __hip_bfloat16* ub = ucm + (size_t)h * M_ + (size_t)b * L_;
    #pragma unroll
    for (int it = 0; it < 4; it++) {
        int e0 = it * 2048 + tid * 8;
        short8 v = *(const short8*)(ub + e0);
        int c = e0 >> 6, e = e0 & 63;
        *(short8*)&ulds[c * 64 + (e ^ ((c & 7) << 3))] = v;
    }
    __syncthreads();
    {
        const __hip_bfloat16* bbase = mw + (size_t)h * 4096 + l15 * 64 + l4 * 8;
        #pragma unroll
        for (int half = 0; half < 2; half++) {
            int g0 = (w + half * 4) * 16;
            int ca = g0 + l15;
            f32x4 acc[4];
            #pragma unroll
            for (int nj = 0; nj < 4; nj++) acc[nj] = (f32x4)0.f;
            #pragma unroll
            for (int ks = 0; ks < 2; ks++) {
                int e = l4 * 8 + ks * 32;
                bf16x8 a = *(const bf16x8*)&ulds[ca * 64 + (e ^ ((ca & 7) << 3))];
                #pragma unroll
                for (int nj = 0; nj < 4; nj++) {
                    bf16x8 bb = *(const bf16x8*)(bbase + nj * 16 * 64 + ks * 32);
                    acc[nj] = __builtin_amdgcn_mfma_f32_16x16x32_bf16(a, bb, acc[nj], 0, 0, 0);
                }
            }
            #pragma unroll
            for (int nj = 0; nj < 4; nj++)
                #pragma unroll
                for (int r = 0; r < 4; r++) {
                    int c = g0 + l4 * 4 + r, e = nj * 16 + l15;
                    st[c * 64 + (e ^ ((c & 7) << 3))] = __float2bfloat16(acc[nj][r]);
                }
        }
    }
    __syncthreads();
    {
        int s = tid >> 5, n = tid & 31;
        float2 wl = ((const float2*)(ws + OFF_PWLC))[(size_t)layer * H_ * N2_ + h * 32 + n];
        float tr = 0.f, ti = 0.f;
        for (int j = 0; j < 16; j++) {
            int c = s * 16 + j;
            __hip_bfloat162* p = (__hip_bfloat162*)&st[c * 64 + ((2 * n) ^ ((c & 7) << 3))];
            float2 v = __bfloat1622float2(*p);
            float nr = fmaf(wl.x, tr, v.x); nr = fmaf(-wl.y, ti, nr);
            float ni = fmaf(wl.x, ti, v.y); ni = fmaf(wl.y, tr, ni);
            tr = nr; ti = ni;
        }
        segT[s][n][0] = tr; segT[s][n][1] = ti;
        __syncthreads();
        float wr = wl.x, wi = wl.y;
        #pragma unroll
        for (int q = 0; q < 4; q++) {
            float nr = wr * wr - wi * wi, ni = 2.f * wr * wi;
            wr = nr; wi = ni;
        }
        float ar = 0.f, ai = 0.f;
        for (int t = 0; t < s; t++) {
            float Tx = segT[t][n][0], Ty = segT[t][n][1];
            float nr = fmaf(wr, ar, Tx); nr = fmaf(-wi, ai, nr);
            float ni = fmaf(wr, ai, Ty); ni = fmaf(wi, ar, ni);
            ar = nr; ai = ni;
        }
        for (int j = 0; j < 16; j++) {
            int c = s * 16 + j;
            __hip_bfloat162* p = (__hip_bfloat162*)&st[c * 64 + ((2 * n) ^ ((c & 7) << 3))];
            float2 v = __bfloat1622float2(*p);
            *p = __float22bfloat162_rn(make_float2(ar, ai));
            float nr = fmaf(wl.x, ar, v.x); nr = fmaf(-wl.y, ai, nr);
            float ni = fmaf(wl.x, ai, v.y); ni = fmaf(wl.y, ar, ni);
            ar = nr; ai = ni;
        }
    }
    __syncthreads();
    {
        const __hip_bfloat16* bt = mt + (size_t)h * 4096 + l15 * 64 + l4 * 8;
        const __hip_bfloat16* bv = mv + (size_t)h * 4096 + l15 * 64 + l4 * 8;
        float Dh = Dp[layer * H_ + h];
        __hip_bfloat16* yb = ycm + (size_t)h * M_ + (size_t)b * L_;
        #pragma unroll
        for (int half = 0; half < 2; half++) {
            int g0 = (w + half * 4) * 16;
            int ca = g0 + l15;
            f32x4 acc[4];
            #pragma unroll
            for (int nj = 0; nj < 4; nj++) acc[nj] = (f32x4)0.f;
            #pragma unroll
            for (int ks = 0; ks < 2; ks++) {
                int e = l4 * 8 + ks * 32;
                bf16x8 a = *(const bf16x8*)&ulds[ca * 64 + (e ^ ((ca & 7) << 3))];
                #pragma unroll
                for (int nj = 0; nj < 4; nj++) {
                    bf16x8 bb = *(const bf16x8*)(bt + nj * 16 * 64 + ks * 32);
                    acc[nj] = __builtin_amdgcn_mfma_f32_16x16x32_bf16(a, bb, acc[nj], 0, 0, 0);
                }
            }
            #pragma unroll
            for (int ks = 0; ks < 2; ks++) {
                int e = l4 * 8 + ks * 32;
                bf16x8 a = *(const bf16x8*)&st[ca * 64 + (e ^ ((ca & 7) << 3))];
                #pragma unroll
                for (int nj = 0; nj < 4; nj++) {
                    bf16x8 bb = *(const bf16x8*)(bv + nj * 16 * 64 + ks * 32);
                    acc[nj] = __builtin_amdgcn_mfma_f32_16x16x32_bf16(a, bb, acc[nj], 0, 0, 0);
                }
            }
            #pragma unroll
            for (int nj = 0; nj < 4; nj++)
                #pragma unroll
                for (int r = 0; r < 4; r++) {
                    int g = g0 + l4 * 4 + r;
                    int e = nj * 16 + l15;
                    float uv = __bfloat162float(ulds[g * 64 + (e ^ ((g & 7) << 3))]);
                    float v = fmaf(Dh, uv, acc[nj][r]);
                    float gg = 0.7978845608028654f * fmaf(0.044715f * v, v * v, v);
                    float yv = v / (1.f + __expf(-2.f * gg));
                    yb[(size_t)g * 64 + nj * 16 + l15] = __float2bfloat16(yv);
                }
        }
    }
}

// ---------------------------------------------------------------------------
// fused MFMA GLU+LN v10: BM=32, grid 1024. A staged from channel-major ycm
// into pair-interleaved pos-major LDS (dword[pos][130]); A-frags = 2 b64
// reads; bf16 hfr residual prefetched early; epilogue writes bf16 hfr +
// next-layer ucm (lt aliases the A-LDS buffer).
__global__ __launch_bounds__(256) void k_glu_mfma(
    const __hip_bfloat16* __restrict__ ycm,  // [H][M] bf16 cm
    __hip_bfloat16* __restrict__ hfr,        // bf16 fragment-layout
    const __hip_bfloat16* __restrict__ wob,  // [512,256] bf16
    const float* __restrict__ bo, const float* __restrict__ lnw,
    const float* __restrict__ lnb, __hip_bfloat16* __restrict__ un)
{
    __shared__ int buf[4352];                // 17.4 KB: A-tile dwords / lt reuse
    __shared__ float red[4][32][2];
    int tid = threadIdx.x;
    int w = tid >> 6, l = tid & 63, l15 = l & 15, l4 = l >> 4;
    int m0 = blockIdx.x * 32;
    int mi = (m0 >> 5) & 1;
    int nv = w * 64;

    // ---- A stage: thread = (pair p, pos-half ph); 2 channels x 16 positions
    {
        int p = tid & 127, ph = tid >> 7;
        const __hip_bfloat16* s0 = ycm + (size_t)(2 * p) * M_ + m0 + ph * 16;
        const __hip_bfloat16* s1 = s0 + M_;
        short8 y0a = *(const short8*)(s0);
        short8 y0b = *(const short8*)(s0 + 8);
        short8 y1a = *(const short8*)(s1);
        short8 y1b = *(const short8*)(s1 + 8);
        int* dst = buf + ph * 16 * 130 + p;
        #pragma unroll
        for (int j = 0; j < 8; j++) {
            dst[j * 130] = ((int)(unsigned short)y0a[j]) | (((int)(unsigned short)y1a[j]) << 16);
            dst[(8 + j) * 130] = ((int)(unsigned short)y0b[j]) | (((int)(unsigned short)y1b[j]) << 16);
        }
    }
    // residual prefetch EARLY (64 B/thread; latency hides under K-loop)
    __hip_bfloat16* hbase = hfr + (size_t)(m0 & ~63) * 256
                            + ((size_t)((mi * 4 + w) * 64 + l)) * 32;
    bf16x8 hraw[4];
    #pragma unroll
    for (int q = 0; q < 4; q++) hraw[q] = *(const bf16x8*)(hbase + q * 8);
    __syncthreads();

    f32x4 accv[2][4], accg[2][4];
    #pragma unroll
    for (int sub = 0; sub < 2; sub++)
        #pragma unroll
        for (int nj = 0; nj < 4; nj++) { accv[sub][nj] = (f32x4)0.f; accg[sub][nj] = (f32x4)0.f; }

    int abase0 = l15 * 130 + l4 * 4;         // dword base, a0 (pos l15)
    #pragma unroll 2
    for (int ks = 0; ks < 8; ks++) {
        int k0 = ks * 32 + l4 * 8;
        union { int2v d[2]; bf16x8 v; } a0u, a1u;
        a0u.d[0] = *(const int2v*)&buf[abase0 + ks * 16];
        a0u.d[1] = *(const int2v*)&buf[abase0 + ks * 16 + 2];
        a1u.d[0] = *(const int2v*)&buf[abase0 + 16 * 130 + ks * 16];
        a1u.d[1] = *(const int2v*)&buf[abase0 + 16 * 130 + ks * 16 + 2];
        bf16x8 a0 = a0u.v;
        bf16x8 a1 = a1u.v;
        #pragma unroll
        for (int nj = 0; nj < 4; nj++) {
            bf16x8 bv = *(const bf16x8*)(wob + (size_t)(nv + nj * 16 + l15) * H_ + k0);
            bf16x8 bg = *(const bf16x8*)(wob + (size_t)(256 + nv + nj * 16 + l15) * H_ + k0);
            accv[0][nj] = __builtin_amdgcn_mfma_f32_16x16x32_bf16(a0, bv, accv[0][nj], 0, 0, 0);
            accg[0][nj] = __builtin_amdgcn_mfma_f32_16x16x32_bf16(a0, bg, accg[0][nj], 0, 0, 0);
            accv[1][nj] = __builtin_amdgcn_mfma_f32_16x16x32_bf16(a1, bv, accv[1][nj], 0, 0, 0);
            accg[1][nj] = __builtin_amdgcn_mfma_f32_16x16x32_bf16(a1, bg, accg[1][nj], 0, 0, 0);
        }
    }

    float bov[4], bog[4], lw[4], lb[4];
    #pragma unroll
    for (int nj = 0; nj < 4; nj++) {
        int cn = nv + nj * 16 + l15;
        bov[nj] = bo[cn]; bog[nj] = bo[256 + cn];
        lw[nj] = lnw[cn]; lb[nj] = lnb[cn];
    }
    #pragma unroll
    for (int sub = 0; sub < 2; sub++) {
        #pragma unroll
        for (int r = 0; r < 4; r++) {
            int lr = sub * 16 + l4 * 4 + r;
            float s = 0.f, ss = 0.f;
            #pragma unroll
            for (int nj = 0; nj < 4; nj++) {
                int idx = sub * 16 + nj * 4 + r;
                float uv = accv[sub][nj][r] + bov[nj];
                float ug = accg[sub][nj][r] + bog[nj];
                float z = uv / (1.f + __expf(-ug));
                float v = z + b2f(hraw[idx >> 3][idx & 7]);
                accv[sub][nj][r] = v;
                s += v; ss += v * v;
            }
            #pragma unroll
            for (int off = 1; off < 16; off <<= 1) {
                s  += __shfl_xor(s, off);
                ss += __shfl_xor(ss, off);
            }
            if (l15 == 0) { red[w][lr][0] = s; red[w][lr][1] = ss; }
        }
    }
    __syncthreads();                 // A reads done -> reuse buf as lt (shorts)
    short* lt = (short*)buf;
    alignas(16) __hip_bfloat16 tmp[32];
    #pragma unroll
    for (int sub = 0; sub < 2; sub++) {
        #pragma unroll
        for (int r = 0; r < 4; r++) {
            int lr = sub * 16 + l4 * 4 + r;
            float s  = red[0][lr][0] + red[1][lr][0] + red[2][lr][0] + red[3][lr][0];
            float ss = red[0][lr][1] + red[1][lr][1] + red[2][lr][1] + red[3][lr][1];
            float mu = s * (1.f / 256.f);
            float var = ss * (1.f / 256.f) - mu * mu;
            float rstd = rsqrtf(var + 1e-5f);
            #pragma unroll
            for (int nj = 0; nj < 4; nj++) {
                int cn = nv + nj * 16 + l15;
                int idx = sub * 16 + nj * 4 + r;
                float val = (accv[sub][nj][r] - mu) * rstd * lw[nj] + lb[nj];
                __hip_bfloat16 bval = __float2bfloat16(val);
                tmp[idx] = bval;
                lt[cn * 34 + lr] = *(short*)&bval;
            }
        }
    }
    // hfr write: 64 B/thread contiguous
    #pragma unroll
    for (int q = 0; q < 4; q++)
        *(short8*)(hbase + q * 8) = *(short8*)&tmp[q * 8];
    __syncthreads();
    {   // ucm write: thread = channel, 32 positions
        #pragma unroll
        for (int q = 0; q < 4; q++)
            *(short8*)(un + (size_t)tid * M_ + m0 + q * 8)
                = *(short8*)&lt[tid * 34 + q * 8];
    }
}

// ---------------------------------------------------------------------------
// decoder: reads bf16 hfr (fragment layout) via LDS unscramble; 64-pos tiles
__global__ __launch_bounds__(256) void k_decoder(const __hip_bfloat16* __restrict__ hfr,
    const float* __restrict__ out_W, const float* __restrict__ out_b,
    float* __restrict__ out)
{
    __shared__ float hs[64][260];
    __shared__ float wl[10][260];
    int m0 = blockIdx.x * 64;
    int tid = threadIdx.x;
    #pragma unroll
    for (int half = 0; half < 2; half++) {
        int cid = half * 256 + tid;          // tid32 chunk id
        int cw = cid >> 6, cl = cid & 63;
        int cmi = cw >> 2, cnq = cw & 3, cl4 = cl >> 4, cl15 = cl & 15;
        const bf16x8* src = (const bf16x8*)(hfr + (size_t)m0 * 256 + (size_t)cid * 32);
        bf16x8 raw[4];
        #pragma unroll
        for (int q = 0; q < 4; q++) raw[q] = src[q];
        #pragma unroll
        for (int sub = 0; sub < 2; sub++)
            #pragma unroll
            for (int nj = 0; nj < 4; nj++) {
                int row = cmi * 32 + sub * 16 + cl4 * 4;
                int col = cnq * 64 + nj * 16 + cl15;
                #pragma unroll
                for (int r = 0; r < 4; r++) {
                    int idx = sub * 16 + nj * 4 + r;
                    hs[row + r][col] = b2f(raw[idx >> 3][idx & 7]);
                }
            }
    }
    for (int q = tid; q < 640; q += 256) {
        int r = q / 64, k4 = q % 64;
        *(float4*)&wl[r][k4 * 4] = ((const float4*)out_W)[q];
    }
    __syncthreads();
    int slot = tid & 15;
    if (slot < DOUT) {
        #pragma unroll
        for (int pass = 0; pass < 4; pass++) {
            int pl = pass * 16 + (tid >> 4);
            float a0 = 0.f, a1 = 0.f, a2 = 0.f, a3 = 0.f;
            #pragma unroll 8
            for (int k = 0; k < 256; k += 4) {
                a0 = fmaf(hs[pl][k + 0], wl[slot][k + 0], a0);
                a1 = fmaf(hs[pl][k + 1], wl[slot][k + 1], a1);
                a2 = fmaf(hs[pl][k + 2], wl[slot][k + 2], a2);
                a3 = fmaf(hs[pl][k + 3], wl[slot][k + 3], a3);
            }
            out[(size_t)(m0 + pl) * DOUT + slot] = (a0 + a1) + (a2 + a3) + out_b[slot];
        }
    }
}

// ---------------------------------------------------------------------------
extern "C" void kernel_launch(void* const* d_in, const int* in_sizes, int n_in,
                              void* d_out, int out_size, void* d_ws, size_t ws_size,
                              hipStream_t stream)
{
    (void)in_sizes; (void)n_in; (void)out_size; (void)ws_size;
    const float* x        = (const float*)d_in[0];
    const float* enc_W    = (const float*)d_in[1];
    const float* enc_b    = (const float*)d_in[2];
    const float* log_dt   = (const float*)d_in[3];
    const float* log_A_re = (const float*)d_in[4];
    const float* A_im     = (const float*)d_in[5];
    const float* C_re     = (const float*)d_in[6];
    const float* C_im     = (const float*)d_in[7];
    const float* Dp       = (const float*)d_in[8];
    const float* Wo       = (const float*)d_in[9];
    const float* bo       = (const float*)d_in[10];
    const float* lnw      = (const float*)d_in[11];
    const float* lnb      = (const float*)d_in[12];
    const float* out_W    = (const float*)d_in[13];
    const float* out_b    = (const float*)d_in[14];
    float* ws = (float*)d_ws;
    __hip_bfloat16* hfr = (__hip_bfloat16*)(ws + OFF_H);
    __hip_bfloat16* ucm = (__hip_bfloat16*)(ws + OFF_UCM);
    __hip_bfloat16* ycm = (__hip_bfloat16*)(ws + OFF_YCM);
    __hip_bfloat16* mt = (__hip_bfloat16*)(ws + OFF_MT);
    __hip_bfloat16* mw = (__hip_bfloat16*)(ws + OFF_MW);
    __hip_bfloat16* mv = (__hip_bfloat16*)(ws + OFF_MV);
    __hip_bfloat16* wob = (__hip_bfloat16*)(ws + OFF_WOB);

    k_params<<<NL_ * H_ * N2_ / 256, 256, 0, stream>>>(log_dt, log_A_re, A_im, C_re, C_im, ws);
    dim3 tb(32, 8);
    k_transpose<<<dim3(DIN / 32, H_ / 32), tb, 0, stream>>>(enc_W, ws + OFF_EWT, H_, DIN);
    k_wcvt<<<(NL_ * 2 * H_ * H_ / 4 + 255) / 256, 256, 0, stream>>>(Wo, wob, NL_ * 2 * H_ * H_ / 4);
    k_encoder<<<M_ / 32, 256, 0, stream>>>(x, ws + OFF_EWT, enc_b, hfr, ucm);
    for (int i = 0; i < NL_; i++) {
        k_mats<<<H_, 256, 0, stream>>>(ws, i, mt, mw, mv);
        k_ssm<<<H_ * B_, 256, 0, stream>>>(ucm, mt, mw, mv, ws, i, Dp, ycm);
        k_glu_mfma<<<M_ / 32, 256, 0, stream>>>(ycm, hfr,
            wob + (size_t)i * 2 * H_ * H_, bo + (size_t)i * 2 * H_,
            lnw + (size_t)i * H_, lnb + (size_t)i * H_, ucm);
    }
    k_decoder<<<M_ / 64, 256, 0, stream>>>(hfr, out_W, out_b, (float*)d_out);
}